// Round 12
// baseline (252.359 us; speedup 1.0000x reference)
//
#include <hip/hip_runtime.h>
#include <hip/hip_bf16.h>
#include <hip/hip_fp16.h>
#include <math.h>

// ---------------------------------------------------------------------------
// DisplacementTensors: rad = MLP(radial_encode(|r|)) depends only on |r| ->
// tabulate per-channel (ra,rv,rd,pad) 16-B quads (128 f32/row = 512 B,
// 8192 entries, 4 MB, L2/L3-resident).
// R18 lesson: total ≈ k_nodes2 + 157 us ACROSS ALL ROUNDS -- CSR-build WORK
// is negligible; the residual is fixed per-dispatch cost (45-us harness fill
// + ~10 us launch/ramp/drain x 7 kernels).  R19-R22: launch count 7 -> 5:
//   k_table  : table build (weights read direct, L1-resident; absorbs k_prep)
//              + tail blocks zero counts
//   k_rank   : rank[e] = atomicAdd(&counts[src[e]], 1)   (640k L2 atomics)
//   k_scan   : single-block prefix -> rowstart
//   k_place2 : pos = rowstart[src] + rank; compute + write payload (no LDS)
//   k_nodes2 : TWO nodes per wave, asm-forced 8-wide load batches (R17)
// R20 fixed R19's one-char bug (ldf(w_d,..,sd) passed float accum as the
// f32 flag -> Output 2 garbage).  R21/R22 = resubmits after infra failures
// (R9 ran this exact structure to completion, so the source is exonerated).
// Payload order within a node is nondeterministic (atomic rank) -- only
// permutes fp32 accumulation order; output tolerance (bf16) dwarfs it.
// k_nodes2 ladder R11-R17: 48.9 -> ~44 us (interleaved 16-B table quad, asm
// 8x global_load_dwordx4 batches; NT stores = 3x write amplification trap;
// source-level ILP defeated by pressure-minimizing scheduler -> asm blocks).
// ---------------------------------------------------------------------------

#define TSIZE 8192
#define DMAX  2.0f           // RBF centers <=1, width 1/8 -> F const beyond ~2
#define EPB   4              // entries per block in k_table
#define NPB   4              // waves per block in k_nodes2 (8 nodes/block)
#define ROWB  512            // table row bytes (32 ch x 16 B)
#define ROWF  128            // table row floats

typedef float        f32x4 __attribute__((ext_vector_type(4)));
typedef unsigned int u32x2 __attribute__((ext_vector_type(2)));

struct TE { float r, v, d; };   // table triple view (12 of the 16 B)

__device__ __forceinline__ float lrelu(float x) { return x > 0.0f ? x : 0.1f * x; }

__device__ __forceinline__ float ldf(const void* p, int i, bool f32) {
    return f32 ? ((const float*)p)[i]
               : __uint_as_float(((unsigned int)((const unsigned short*)p)[i]) << 16);
}
__device__ __forceinline__ void stf(void* p, size_t i, float v, bool f32) {
    if (f32) ((float*)p)[i] = v;
    else     ((__hip_bfloat16*)p)[i] = __float2bfloat16(v);
}

__device__ __forceinline__ bool detect_f32(const void* r) {
    const unsigned short* p = (const unsigned short*)r;
    int bad = 0;
#pragma unroll 8
    for (int i = 0; i < 128; i++) {
        float v = __uint_as_float(((unsigned int)p[i]) << 16);
        bad |= (!isfinite(v) || fabsf(v) > 1e5f) ? 1 : 0;
    }
    return bad != 0;
}

// 8 independent 16-B loads in ONE asm block: scheduler cannot split it, so
// all 8 results are simultaneously live.  Internal vmcnt(0) + data-dependence
// on the outputs orders all consumers after the loads complete.
__device__ __forceinline__ void load8x16(
    const void* p0, const void* p1, const void* p2, const void* p3,
    const void* p4, const void* p5, const void* p6, const void* p7,
    f32x4& q0, f32x4& q1, f32x4& q2, f32x4& q3,
    f32x4& q4, f32x4& q5, f32x4& q6, f32x4& q7) {
    asm volatile(
        "global_load_dwordx4 %0, %8, off\n\t"
        "global_load_dwordx4 %1, %9, off\n\t"
        "global_load_dwordx4 %2, %10, off\n\t"
        "global_load_dwordx4 %3, %11, off\n\t"
        "global_load_dwordx4 %4, %12, off\n\t"
        "global_load_dwordx4 %5, %13, off\n\t"
        "global_load_dwordx4 %6, %14, off\n\t"
        "global_load_dwordx4 %7, %15, off\n\t"
        "s_waitcnt vmcnt(0)"
        : "=&v"(q0), "=&v"(q1), "=&v"(q2), "=&v"(q3),
          "=&v"(q4), "=&v"(q5), "=&v"(q6), "=&v"(q7)
        : "v"(p0), "v"(p1), "v"(p2), "v"(p3),
          "v"(p4), "v"(p5), "v"(p6), "v"(p7));
}

// --- table build (absorbs weight concat + counts zeroing) ------------------
// blocks [0, TSIZE/EPB): table entries; blocks beyond: zero counts.
// Weights read directly (L1-resident: largest = w2, 16 KB f32).
// table row e: 32 x (ra, rv, rd, pad) 16-B quads -> lane a gathers ONE
// aligned dwordx4 at e*512 + a*16 in k_nodes2.
__global__ void __launch_bounds__(64 * EPB) k_table(
    const void* __restrict__ r_ij,
    const void* w_rad, const void* b_rad, const void* w_direct,
    const void* w1, const void* b1, const void* w2, const void* b2,
    const void* w3, const void* b3, const void* w_v, const void* w_d,
    float* __restrict__ tabI, int* __restrict__ counts, int N) {
    __shared__ float Lh[EPB][32], Lt1[EPB][64], Lt2[EPB][64], Lrad[EPB][32];

    const int TB = TSIZE / EPB;
    if (blockIdx.x >= TB) {
        const int i = (blockIdx.x - TB) * (64 * EPB) + threadIdx.x;
        if (i < N) counts[i] = 0;
        return;
    }

    const bool f32 = detect_f32(r_ij);
    const int s = threadIdx.x >> 6;
    const int j = threadIdx.x & 63;
    const int e = blockIdx.x * EPB + s;
    const float d = (float)e * (DMAX / (float)(TSIZE - 1));

    float enc[8];
#pragma unroll
    for (int k = 0; k < 8; k++) {
        float t = (d - (float)k * (1.0f / 7.0f)) * 8.0f;
        enc[k] = expf(-t * t);
    }

    if (j < 32) {
        float hv = ldf(b_rad, j, f32);
#pragma unroll
        for (int k = 0; k < 8; k++)
            hv = fmaf(enc[k], ldf(w_rad, k * 32 + j, f32), hv);
        Lh[s][j] = hv;
    }
    __syncthreads();

    {
        float v = ldf(b1, j, f32);
#pragma unroll
        for (int i = 0; i < 32; i++)
            v = fmaf(Lh[s][i], ldf(w1, i * 64 + j, f32), v);
        Lt1[s][j] = lrelu(v);
    }
    __syncthreads();

    {
        float v = ldf(b2, j, f32);
#pragma unroll
        for (int i = 0; i < 64; i++)
            v = fmaf(Lt1[s][i], ldf(w2, i * 64 + j, f32), v);
        Lt2[s][j] = lrelu(v);
    }
    __syncthreads();

    if (j < 32) {
        float v = ldf(b3, j, f32);
#pragma unroll
        for (int i = 0; i < 64; i++)
            v = fmaf(Lt2[s][i], ldf(w3, i * 32 + j, f32), v);
#pragma unroll
        for (int i = 0; i < 32; i++)
            v = fmaf(Lh[s][i], ldf(w_direct, i * 32 + j, f32), v);
        Lrad[s][j] = v;
    }
    __syncthreads();

    if (j < 32) {
        float sv = 0.0f, sd = 0.0f;
#pragma unroll
        for (int i = 0; i < 32; i++) {
            float ri = Lrad[s][i];
            sv = fmaf(ri, ldf(w_v, i * 32 + j, f32), sv);
            sd = fmaf(ri, ldf(w_d, i * 32 + j, f32), sd);
        }
        float* row = tabI + (size_t)e * ROWF + j * 4;
        row[0] = Lrad[s][j];
        row[1] = sv;
        row[2] = sd;
        row[3] = 0.0f;
    }
}

// --- CSR pass 1: per-edge rank via global atomics --------------------------
__global__ void __launch_bounds__(256) k_rank(const int* __restrict__ src,
                                              int* __restrict__ counts,
                                              unsigned short* __restrict__ rank,
                                              int E) {
    const int e = blockIdx.x * 256 + threadIdx.x;
    if (e < E) rank[e] = (unsigned short)atomicAdd(&counts[src[e]], 1);
}

// --- CSR pass 2: single-block prefix sum -> rowstart -----------------------
__global__ void __launch_bounds__(1024) k_scan(const int* __restrict__ counts,
                                               int* __restrict__ rowstart,
                                               int N, int E) {
    __shared__ int part[1024];
    const int t = threadIdx.x;
    const int CH = (N + 1023) / 1024;
    const int lo = t * CH;
    const int hi = min(lo + CH, N);
    int s = 0;
    for (int i = lo; i < hi; i++) s += counts[i];
    part[t] = s;
    __syncthreads();
    for (int off = 1; off < 1024; off <<= 1) {
        int v = part[t];
        int w = (t >= off) ? part[t - off] : 0;
        __syncthreads();
        part[t] = v + w;
        __syncthreads();
    }
    int run = (t == 0) ? 0 : part[t - 1];
    for (int i = lo; i < hi; i++) { rowstart[i] = run; run += counts[i]; }
    if (t == 0) rowstart[N] = E;
}

// --- CSR pass 3: place payload (no LDS; pos = rowstart[src] + rank) --------
template <bool P16>
__global__ void __launch_bounds__(256) k_place2(
        const int* __restrict__ src, const unsigned short* __restrict__ rank,
        const int* __restrict__ rowstart, const void* __restrict__ r_ij,
        void* __restrict__ epsv, int E) {
    const bool f32 = detect_f32(r_ij);
    const int e = blockIdx.x * 256 + threadIdx.x;
    if (e >= E) return;
    const int pos = rowstart[src[e]] + (int)rank[e];
    const float x = ldf(r_ij, 3 * e + 0, f32);
    const float y = ldf(r_ij, 3 * e + 1, f32);
    const float z = ldf(r_ij, 3 * e + 2, f32);
    const float d2 = x * x + y * y + z * z;
    const float inv = rsqrtf(1.0f + 49.0f * d2);  // tens_sigmoid(7r)
    const float u = fminf(sqrtf(d2), DMAX) * ((float)(TSIZE - 1) / DMAX);
    const int ti = (int)(u + 0.5f);               // nearest, <= TSIZE-1
    const float rs0 = 7.0f * x * inv, rs1 = 7.0f * y * inv, rs2 = 7.0f * z * inv;
    if (P16) {
        ((float4*)epsv)[pos] =
            make_float4(rs0, rs1, rs2, __int_as_float(ti * ROWB));
    } else {
        const unsigned int h0 = __half_as_ushort(__float2half(rs0));
        const unsigned int h1 = __half_as_ushort(__float2half(rs1));
        const unsigned int h2 = __half_as_ushort(__float2half(rs2));
        ((uint2*)epsv)[pos] =
            make_uint2(h0 | (h1 << 16), h2 | ((unsigned)ti << 16));
    }
}

// --- per-node accumulation: TWO nodes per wave, asm-forced 8-wide loads ----
#define ACC16(Q, U)                                                           \
    do {                                                                      \
        const float x = (Q).x, y = (Q).y, z = (Q).z;                          \
        accA += (U).x;                                                        \
        v0 += (U).y * x; v1 += (U).y * y; v2 += (U).y * z;                    \
        const float _tx = (U).z * x, _ty = (U).z * y, _tz = (U).z * z;        \
        d00 += _tx * x; d01 += _tx * y; d02 += _tx * z;                       \
        d10 += _ty * x; d11 += _ty * y; d12 += _ty * z;                       \
        d20 += _tz * x; d21 += _tz * y; d22 += _tz * z;                       \
    } while (0)

template <bool P16>
__global__ void __launch_bounds__(64 * NPB, 4) k_nodes2(
    const void* __restrict__ epsv,
    const int* __restrict__ rowstart,
    const float* __restrict__ tabI,
    const void* __restrict__ r_ij,
    void* __restrict__ out, int N) {
    const int wave = threadIdx.x >> 6;
    const int lane = threadIdx.x & 63;
    const int n0 = (blockIdx.x * NPB + wave) * 2;
    const int a = lane & 31;
    const int half = lane >> 5;
    const int myn = n0 + half;
    const bool f32 = detect_f32(r_ij);
    const char* tabA = (const char*)tabI + a * 16;   // 16-B quad base

    int s0 = 0, s1 = 0;
    if (myn < N) { s0 = rowstart[myn]; s1 = rowstart[myn + 1]; }
    const int mylen = s1 - s0;
    const int lenA = __shfl(mylen, 0);
    const int lenB = __shfl(mylen, 32);
    const int minl = min(lenA, lenB);
    const int maxl = max(lenA, lenB);
    const int mclamp = max(mylen - 1, 0);

    float accA = 0.f, v0 = 0.f, v1 = 0.f, v2 = 0.f;
    float d00 = 0.f, d01 = 0.f, d02 = 0.f,
          d10 = 0.f, d11 = 0.f, d12 = 0.f,
          d20 = 0.f, d21 = 0.f, d22 = 0.f;

    if (P16) {
        int i = 0;
        // ---- main: unpredicated 8-wide batches up to minl ----
        for (; i + 8 <= minl; i += 8) {
            const char* pb = (const char*)epsv + (size_t)(s0 + i) * 16;
            f32x4 q0, q1, q2, q3, q4, q5, q6, q7;
            load8x16(pb, pb + 16, pb + 32, pb + 48,
                     pb + 64, pb + 80, pb + 96, pb + 112,
                     q0, q1, q2, q3, q4, q5, q6, q7);
            f32x4 u0, u1, u2, u3, u4, u5, u6, u7;
            load8x16(tabA + __float_as_int(q0.w), tabA + __float_as_int(q1.w),
                     tabA + __float_as_int(q2.w), tabA + __float_as_int(q3.w),
                     tabA + __float_as_int(q4.w), tabA + __float_as_int(q5.w),
                     tabA + __float_as_int(q6.w), tabA + __float_as_int(q7.w),
                     u0, u1, u2, u3, u4, u5, u6, u7);
            ACC16(q0, u0); ACC16(q1, u1); ACC16(q2, u2); ACC16(q3, u3);
            ACC16(q4, u4); ACC16(q5, u5); ACC16(q6, u6); ACC16(q7, u7);
        }
        // ---- remainder: predicated 8-wide batches up to maxl ----
        for (; i < maxl; i += 8) {
            float m0, m1, m2, m3, m4, m5, m6, m7;
#define TIDX(K) ((i + K) < mylen ? (i + K) : mclamp)
#define TPTR(K) ((const char*)epsv + (size_t)(s0 + TIDX(K)) * 16)
            m0 = (i + 0 < mylen) ? 1.f : 0.f;
            m1 = (i + 1 < mylen) ? 1.f : 0.f;
            m2 = (i + 2 < mylen) ? 1.f : 0.f;
            m3 = (i + 3 < mylen) ? 1.f : 0.f;
            m4 = (i + 4 < mylen) ? 1.f : 0.f;
            m5 = (i + 5 < mylen) ? 1.f : 0.f;
            m6 = (i + 6 < mylen) ? 1.f : 0.f;
            m7 = (i + 7 < mylen) ? 1.f : 0.f;
            f32x4 q0, q1, q2, q3, q4, q5, q6, q7;
            load8x16(TPTR(0), TPTR(1), TPTR(2), TPTR(3),
                     TPTR(4), TPTR(5), TPTR(6), TPTR(7),
                     q0, q1, q2, q3, q4, q5, q6, q7);
#undef TPTR
#undef TIDX
            f32x4 u0, u1, u2, u3, u4, u5, u6, u7;
            load8x16(tabA + __float_as_int(q0.w), tabA + __float_as_int(q1.w),
                     tabA + __float_as_int(q2.w), tabA + __float_as_int(q3.w),
                     tabA + __float_as_int(q4.w), tabA + __float_as_int(q5.w),
                     tabA + __float_as_int(q6.w), tabA + __float_as_int(q7.w),
                     u0, u1, u2, u3, u4, u5, u6, u7);
#define SAPX(K)                                                               \
            do { f32x4 uu = u##K; uu.x *= m##K; uu.y *= m##K; uu.z *= m##K;   \
                 ACC16(q##K, uu); } while (0)
            SAPX(0); SAPX(1); SAPX(2); SAPX(3);
            SAPX(4); SAPX(5); SAPX(6); SAPX(7);
#undef SAPX
        }
    } else {
        // ---- P8 fallback payload path (plain C, rarely used) ----
        for (int i = 0; i < maxl; i++) {
            if (i < mylen) {
                const u32x2 qh = *((const u32x2*)epsv + (s0 + i));
                const float x = __half2float(__ushort_as_half(
                    (unsigned short)(qh.x & 0xffffu)));
                const float y = __half2float(__ushort_as_half(
                    (unsigned short)(qh.x >> 16)));
                const float z = __half2float(__ushort_as_half(
                    (unsigned short)(qh.y & 0xffffu)));
                const TE t = *(const TE*)(tabA + (int)(qh.y >> 16) * ROWB);
                accA += t.r;
                v0 += t.v * x; v1 += t.v * y; v2 += t.v * z;
                const float _tx = t.d * x, _ty = t.d * y, _tz = t.d * z;
                d00 += _tx * x; d01 += _tx * y; d02 += _tx * z;
                d10 += _ty * x; d11 += _ty * y; d12 += _ty * z;
                d20 += _tz * x; d21 += _tz * y; d22 += _tz * z;
            }
        }
    }

    if (myn >= N) return;
    const size_t baseV = (size_t)N * 32;
    const size_t baseD = (size_t)N * 128;
    stf(out, (size_t)myn * 32 + a, accA, f32);
    const size_t vb = baseV + (size_t)myn * 96 + a * 3;
    stf(out, vb + 0, v0, f32);
    stf(out, vb + 1, v1, f32);
    stf(out, vb + 2, v2, f32);
    const size_t db = baseD + (size_t)myn * 288 + a * 9;
    stf(out, db + 0, d00, f32);
    stf(out, db + 1, d01, f32);
    stf(out, db + 2, d02, f32);
    stf(out, db + 3, d10, f32);
    stf(out, db + 4, d11, f32);
    stf(out, db + 5, d12, f32);
    stf(out, db + 6, d20, f32);
    stf(out, db + 7, d21, f32);
    stf(out, db + 8, d22, f32);
}

// --- fallback (ws too small for payload): perm + on-the-fly recompute ------
__global__ void __launch_bounds__(256) k_place_g(
        const int* __restrict__ src, const unsigned short* __restrict__ rank,
        const int* __restrict__ rowstart, int* __restrict__ perm, int E) {
    const int e = blockIdx.x * 256 + threadIdx.x;
    if (e < E) perm[rowstart[src[e]] + (int)rank[e]] = e;
}
__global__ void __launch_bounds__(256) k_nodes_fb(
    const int* __restrict__ perm, const void* __restrict__ r_ij,
    const int* __restrict__ rowstart, const float* __restrict__ tabI,
    void* __restrict__ out, int N) {
    const int wave = threadIdx.x >> 6;
    const int lane = threadIdx.x & 63;
    const int n = blockIdx.x * 4 + wave;
    if (n >= N) return;
    const int a = lane & 31;
    const bool hi = (lane >> 5) != 0;
    const bool f32 = detect_f32(r_ij);
    const int s0 = rowstart[n], s1 = rowstart[n + 1];
    float accR = 0.f, acc1 = 0.f, acc2 = 0.f, acc3 = 0.f,
          acc4 = 0.f, acc5 = 0.f, acc6 = 0.f;
    for (int idx = s0; idx < s1; idx++) {
        const int e = perm[idx];
        const float x0 = ldf(r_ij, 3 * e + 0, f32);
        const float y0 = ldf(r_ij, 3 * e + 1, f32);
        const float z0 = ldf(r_ij, 3 * e + 2, f32);
        const float d2 = x0 * x0 + y0 * y0 + z0 * z0;
        const float inv = rsqrtf(1.0f + 49.0f * d2);
        const float x = 7.0f * x0 * inv, y = 7.0f * y0 * inv, z = 7.0f * z0 * inv;
        const float u = fminf(sqrtf(d2), DMAX) * ((float)(TSIZE - 1) / DMAX);
        const int b = (int)(u + 0.5f) * ROWF + a * 4;   // padded row
        const float ra = tabI[b], rv = tabI[b + 1], rd = tabI[b + 2];
        const float b1 = (hi ? rd : rv) * (hi ? y : 1.0f);
        const float b2 = rd * (hi ? z : x);
        accR += ra;
        acc1 += b1 * x; acc2 += b1 * y; acc3 += b1 * z;
        acc4 += b2 * x; acc5 += b2 * y; acc6 += b2 * z;
    }
    const size_t baseV = (size_t)N * 32;
    const size_t baseD = (size_t)N * 128;
    if (!hi) {
        stf(out, (size_t)n * 32 + a, accR, f32);
        const size_t vb = baseV + (size_t)n * 96 + a * 3;
        stf(out, vb + 0, acc1, f32);
        stf(out, vb + 1, acc2, f32);
        stf(out, vb + 2, acc3, f32);
        const size_t db = baseD + (size_t)n * 288 + a * 9;
        stf(out, db + 0, acc4, f32);
        stf(out, db + 1, acc5, f32);
        stf(out, db + 2, acc6, f32);
    } else {
        const size_t db = baseD + (size_t)n * 288 + a * 9;
        stf(out, db + 3, acc1, f32);
        stf(out, db + 4, acc2, f32);
        stf(out, db + 5, acc3, f32);
        stf(out, db + 6, acc4, f32);
        stf(out, db + 7, acc5, f32);
        stf(out, db + 8, acc6, f32);
    }
}

extern "C" void kernel_launch(void* const* d_in, const int* in_sizes, int n_in,
                              void* d_out, int out_size, void* d_ws, size_t ws_size,
                              hipStream_t stream) {
    const void* r_ij     = d_in[0];
    const void* w_rad    = d_in[1];
    const void* b_rad    = d_in[2];
    const void* w_direct = d_in[3];
    const void* w1       = d_in[4];
    const void* b1       = d_in[5];
    const void* w2       = d_in[6];
    const void* b2       = d_in[7];
    const void* w3       = d_in[8];
    const void* b3       = d_in[9];
    const void* w_v      = d_in[10];
    const void* w_d      = d_in[11];
    const int* edges_src = (const int*)d_in[12];

    const int E = in_sizes[12];
    const int N = out_size / 416;   // 32 + 96 + 288 per node
    const int TB = TSIZE / EPB;
    const int ZB = (N + 64 * EPB - 1) / (64 * EPB);   // counts-zero blocks
    const int EB = (E + 255) / 256;                    // per-edge blocks
    const int nodeBlocks = (N + 2 * NPB - 1) / (2 * NPB);

    // common tail: tabI (4 MB) + counts N + rowstart N+1 + rank E (u16)
    const size_t tailBytes = (size_t)TSIZE * ROWF * 4
                           + ((size_t)N + N + 1) * 4 + (size_t)E * 2 + 64;
    const bool p16 = ws_size >= (size_t)E * 16 + tailBytes;
    const bool p8  = !p16 && ws_size >= (size_t)E * 8 + tailBytes;

    char* w = (char*)d_ws;
    if (p16 || p8) {
        const size_t slot = (size_t)E * (p16 ? 16 : 8);
        void* eps      = (void*)w;
        float* tabI    = (float*)(w + slot);
        int* counts    = (int*)(tabI + (size_t)TSIZE * ROWF);
        int* rowstart  = counts + N;          // N+1
        unsigned short* rank = (unsigned short*)(rowstart + N + 1);   // E u16

        k_table<<<TB + ZB, 64 * EPB, 0, stream>>>(
            r_ij, w_rad, b_rad, w_direct, w1, b1, w2, b2, w3, b3, w_v, w_d,
            tabI, counts, N);
        k_rank<<<EB, 256, 0, stream>>>(edges_src, counts, rank, E);
        k_scan<<<1, 1024, 0, stream>>>(counts, rowstart, N, E);
        if (p16) {
            k_place2<true><<<EB, 256, 0, stream>>>(
                edges_src, rank, rowstart, r_ij, eps, E);
            k_nodes2<true><<<nodeBlocks, 64 * NPB, 0, stream>>>(
                eps, rowstart, tabI, r_ij, d_out, N);
        } else {
            k_place2<false><<<EB, 256, 0, stream>>>(
                edges_src, rank, rowstart, r_ij, eps, E);
            k_nodes2<false><<<nodeBlocks, 64 * NPB, 0, stream>>>(
                eps, rowstart, tabI, r_ij, d_out, N);
        }
    } else {
        // fallback: perm-indexed nodes, on-the-fly recompute
        int* perm      = (int*)w;             // E
        float* tabI    = (float*)(w + (size_t)E * 4);
        int* counts    = (int*)(tabI + (size_t)TSIZE * ROWF);
        int* rowstart  = counts + N;          // N+1
        unsigned short* rank = (unsigned short*)(rowstart + N + 1);   // E u16

        k_table<<<TB + ZB, 64 * EPB, 0, stream>>>(
            r_ij, w_rad, b_rad, w_direct, w1, b1, w2, b2, w3, b3, w_v, w_d,
            tabI, counts, N);
        k_rank<<<EB, 256, 0, stream>>>(edges_src, counts, rank, E);
        k_scan<<<1, 1024, 0, stream>>>(counts, rowstart, N, E);
        k_place_g<<<EB, 256, 0, stream>>>(edges_src, rank, rowstart, perm, E);
        k_nodes_fb<<<(N + 3) / 4, 256, 0, stream>>>(
            perm, r_ij, rowstart, tabI, d_out, N);
    }
}

// Round 13
// 211.718 us; speedup vs baseline: 1.1920x; 1.1920x over previous
//
#include <hip/hip_runtime.h>
#include <hip/hip_bf16.h>
#include <hip/hip_fp16.h>
#include <math.h>

// ---------------------------------------------------------------------------
// DisplacementTensors: rad = MLP(radial_encode(|r|)) depends only on |r| ->
// tabulate per-channel (ra,rv,rd,pad) 16-B quads (128 f32/row = 512 B,
// 8192 entries, 4 MB, L2/L3-resident).
// R18: total ≈ k_nodes2 + 157 us across all rounds -> residual is fixed
// per-dispatch cost, not CSR work.  R19-R22 cut 7 -> 5 launches but R22's
// k_table read bf16 weights per-FMA (scalar 2-B branchy loads) -> 49 us
// (10x regression, Common-mistake #2).  R23: keep 5 launches, restore the
// f32 wcat pre-concat, and merge table+rank into ONE dispatch:
//   k_prep    : flag + weight->f32 wcat concat + zero counts  (~91 blocks)
//   k_tabrank : blocks [0,TB) table build FROM WCAT (fast R8 path);
//               blocks [TB,TB+EB) rank[e] = atomicAdd(&counts[src[e]],1)
//   k_scan    : single-block prefix -> rowstart
//   k_place2  : pos = rowstart[src]+rank; payload write (flag read, not
//               per-thread detect_f32 -- R22 ran 128 loads/thread!)
//   k_nodes2  : TWO nodes per wave, asm-forced 8-wide load batches (R17)
// Payload order within a node nondeterministic (atomic rank) -- only
// permutes fp32 accumulation order; bf16 output tolerance dwarfs it.
// k_nodes2 ladder R11-R17: 48.9 -> ~44 us (16-B table quad gather, asm
// 8x global_load_dwordx4 batches; NT stores = 3x write amplification trap;
// source-level ILP defeated by pressure-minimizing scheduler -> asm blocks).
// ---------------------------------------------------------------------------

#define TSIZE 8192
#define DMAX  2.0f           // RBF centers <=1, width 1/8 -> F const beyond ~2
#define EPB   4              // entries per block in k_tabrank table section
#define NPB   4              // waves per block in k_nodes2 (8 nodes/block)
#define ROWB  512            // table row bytes (32 ch x 16 B)
#define ROWF  128            // table row floats

// f32 concat-weight offsets (floats)
#define O_WRAD 0
#define O_BRAD 256
#define O_WDIR 288
#define O_W1   1312
#define O_B1   3360
#define O_W2   3424
#define O_B2   7520
#define O_W3   7584
#define O_B3   9632
#define O_WV   9664
#define O_WD   10688
#define W_TOT  11712

typedef float        f32x4 __attribute__((ext_vector_type(4)));
typedef unsigned int u32x2 __attribute__((ext_vector_type(2)));

struct TE { float r, v, d; };   // table triple view (12 of the 16 B)

__device__ __forceinline__ float lrelu(float x) { return x > 0.0f ? x : 0.1f * x; }

__device__ __forceinline__ float ldf(const void* p, int i, bool f32) {
    return f32 ? ((const float*)p)[i]
               : __uint_as_float(((unsigned int)((const unsigned short*)p)[i]) << 16);
}
__device__ __forceinline__ void stf(void* p, size_t i, float v, bool f32) {
    if (f32) ((float*)p)[i] = v;
    else     ((__hip_bfloat16*)p)[i] = __float2bfloat16(v);
}

__device__ __forceinline__ bool detect_f32(const void* r) {
    const unsigned short* p = (const unsigned short*)r;
    int bad = 0;
#pragma unroll 8
    for (int i = 0; i < 128; i++) {
        float v = __uint_as_float(((unsigned int)p[i]) << 16);
        bad |= (!isfinite(v) || fabsf(v) > 1e5f) ? 1 : 0;
    }
    return bad != 0;
}

// 8 independent 16-B loads in ONE asm block: scheduler cannot split it, so
// all 8 results are simultaneously live.  Internal vmcnt(0) + data-dependence
// on the outputs orders all consumers after the loads complete.
__device__ __forceinline__ void load8x16(
    const void* p0, const void* p1, const void* p2, const void* p3,
    const void* p4, const void* p5, const void* p6, const void* p7,
    f32x4& q0, f32x4& q1, f32x4& q2, f32x4& q3,
    f32x4& q4, f32x4& q5, f32x4& q6, f32x4& q7) {
    asm volatile(
        "global_load_dwordx4 %0, %8, off\n\t"
        "global_load_dwordx4 %1, %9, off\n\t"
        "global_load_dwordx4 %2, %10, off\n\t"
        "global_load_dwordx4 %3, %11, off\n\t"
        "global_load_dwordx4 %4, %12, off\n\t"
        "global_load_dwordx4 %5, %13, off\n\t"
        "global_load_dwordx4 %6, %14, off\n\t"
        "global_load_dwordx4 %7, %15, off\n\t"
        "s_waitcnt vmcnt(0)"
        : "=&v"(q0), "=&v"(q1), "=&v"(q2), "=&v"(q3),
          "=&v"(q4), "=&v"(q5), "=&v"(q6), "=&v"(q7)
        : "v"(p0), "v"(p1), "v"(p2), "v"(p3),
          "v"(p4), "v"(p5), "v"(p6), "v"(p7));
}

// --- K1: flag + weight->f32 concat + zero counts ---------------------------
__global__ void __launch_bounds__(256) k_prep(
    const void* __restrict__ r_ij,
    const void* w_rad, const void* b_rad, const void* w_direct,
    const void* w1, const void* b1, const void* w2, const void* b2,
    const void* w3, const void* b3, const void* w_v, const void* w_d,
    float* __restrict__ wcat, int* __restrict__ flag,
    int* __restrict__ counts, int N) {
    const int b = blockIdx.x;
    if (b == 0) {
        if (threadIdx.x == 0) flag[0] = detect_f32(r_ij) ? 1 : 0;
    } else if (b <= 11) {
        const bool f32 = detect_f32(r_ij);
        const void* src; int cnt; int off;
        switch (b) {
            case 1:  src = w_rad;    cnt = 256;  off = O_WRAD; break;
            case 2:  src = b_rad;    cnt = 32;   off = O_BRAD; break;
            case 3:  src = w_direct; cnt = 1024; off = O_WDIR; break;
            case 4:  src = w1;       cnt = 2048; off = O_W1;   break;
            case 5:  src = b1;       cnt = 64;   off = O_B1;   break;
            case 6:  src = w2;       cnt = 4096; off = O_W2;   break;
            case 7:  src = b2;       cnt = 64;   off = O_B2;   break;
            case 8:  src = w3;       cnt = 2048; off = O_W3;   break;
            case 9:  src = b3;       cnt = 32;   off = O_B3;   break;
            case 10: src = w_v;      cnt = 1024; off = O_WV;   break;
            default: src = w_d;      cnt = 1024; off = O_WD;   break;
        }
        for (int i = threadIdx.x; i < cnt; i += 256)
            wcat[off + i] = ldf(src, i, f32);
    } else {
        const int i = (b - 12) * 256 + threadIdx.x;
        if (i < N) counts[i] = 0;
    }
}

// --- K2: table build (from wcat) + per-edge rank atomics, one dispatch -----
// blocks [0, TB): table entries (wave = entry, lane = neuron);
// blocks [TB, TB+EB): rank[e] = atomicAdd(&counts[src[e]], 1).
// table row e: 32 x (ra, rv, rd, pad) 16-B quads -> lane a gathers ONE
// aligned dwordx4 at e*512 + a*16 in k_nodes2.
__global__ void __launch_bounds__(64 * EPB) k_tabrank(
    const float* __restrict__ wcat, float* __restrict__ tabI,
    const int* __restrict__ src, int* __restrict__ counts,
    unsigned short* __restrict__ rank, int E) {
    __shared__ float Lh[EPB][32], Lt1[EPB][64], Lt2[EPB][64], Lrad[EPB][32];

    const int TB = TSIZE / EPB;
    if (blockIdx.x >= TB) {
        const int e = (blockIdx.x - TB) * 256 + threadIdx.x;
        if (e < E) rank[e] = (unsigned short)atomicAdd(&counts[src[e]], 1);
        return;
    }

    const int s = threadIdx.x >> 6;
    const int j = threadIdx.x & 63;
    const int e = blockIdx.x * EPB + s;
    const float d = (float)e * (DMAX / (float)(TSIZE - 1));

    float enc[8];
#pragma unroll
    for (int k = 0; k < 8; k++) {
        float t = (d - (float)k * (1.0f / 7.0f)) * 8.0f;
        enc[k] = expf(-t * t);
    }

    if (j < 32) {
        float hv = wcat[O_BRAD + j];
#pragma unroll
        for (int k = 0; k < 8; k++) hv = fmaf(enc[k], wcat[O_WRAD + k * 32 + j], hv);
        Lh[s][j] = hv;
    }
    __syncthreads();

    {
        float v = wcat[O_B1 + j];
#pragma unroll
        for (int i = 0; i < 32; i++) v = fmaf(Lh[s][i], wcat[O_W1 + i * 64 + j], v);
        Lt1[s][j] = lrelu(v);
    }
    __syncthreads();

    {
        float v = wcat[O_B2 + j];
#pragma unroll
        for (int i = 0; i < 64; i++) v = fmaf(Lt1[s][i], wcat[O_W2 + i * 64 + j], v);
        Lt2[s][j] = lrelu(v);
    }
    __syncthreads();

    if (j < 32) {
        float v = wcat[O_B3 + j];
#pragma unroll
        for (int i = 0; i < 64; i++) v = fmaf(Lt2[s][i], wcat[O_W3 + i * 32 + j], v);
#pragma unroll
        for (int i = 0; i < 32; i++) v = fmaf(Lh[s][i], wcat[O_WDIR + i * 32 + j], v);
        Lrad[s][j] = v;
    }
    __syncthreads();

    if (j < 32) {
        float sv = 0.0f, sd = 0.0f;
#pragma unroll
        for (int i = 0; i < 32; i++) {
            float ri = Lrad[s][i];
            sv = fmaf(ri, wcat[O_WV + i * 32 + j], sv);
            sd = fmaf(ri, wcat[O_WD + i * 32 + j], sd);
        }
        float* row = tabI + (size_t)e * ROWF + j * 4;
        row[0] = Lrad[s][j];
        row[1] = sv;
        row[2] = sd;
        row[3] = 0.0f;
    }
}

// --- K3: single-block prefix sum -> rowstart -------------------------------
__global__ void __launch_bounds__(1024) k_scan(const int* __restrict__ counts,
                                               int* __restrict__ rowstart,
                                               int N, int E) {
    __shared__ int part[1024];
    const int t = threadIdx.x;
    const int CH = (N + 1023) / 1024;
    const int lo = t * CH;
    const int hi = min(lo + CH, N);
    int s = 0;
    for (int i = lo; i < hi; i++) s += counts[i];
    part[t] = s;
    __syncthreads();
    for (int off = 1; off < 1024; off <<= 1) {
        int v = part[t];
        int w = (t >= off) ? part[t - off] : 0;
        __syncthreads();
        part[t] = v + w;
        __syncthreads();
    }
    int run = (t == 0) ? 0 : part[t - 1];
    for (int i = lo; i < hi; i++) { rowstart[i] = run; run += counts[i]; }
    if (t == 0) rowstart[N] = E;
}

// --- K4: place payload (pos = rowstart[src] + rank) ------------------------
template <bool P16>
__global__ void __launch_bounds__(256) k_place2(
        const int* __restrict__ src, const unsigned short* __restrict__ rank,
        const int* __restrict__ rowstart, const void* __restrict__ r_ij,
        const int* __restrict__ flag, void* __restrict__ epsv, int E) {
    const bool f32 = flag[0] != 0;
    const int e = blockIdx.x * 256 + threadIdx.x;
    if (e >= E) return;
    const int pos = rowstart[src[e]] + (int)rank[e];
    const float x = ldf(r_ij, 3 * e + 0, f32);
    const float y = ldf(r_ij, 3 * e + 1, f32);
    const float z = ldf(r_ij, 3 * e + 2, f32);
    const float d2 = x * x + y * y + z * z;
    const float inv = rsqrtf(1.0f + 49.0f * d2);  // tens_sigmoid(7r)
    const float u = fminf(sqrtf(d2), DMAX) * ((float)(TSIZE - 1) / DMAX);
    const int ti = (int)(u + 0.5f);               // nearest, <= TSIZE-1
    const float rs0 = 7.0f * x * inv, rs1 = 7.0f * y * inv, rs2 = 7.0f * z * inv;
    if (P16) {
        ((float4*)epsv)[pos] =
            make_float4(rs0, rs1, rs2, __int_as_float(ti * ROWB));
    } else {
        const unsigned int h0 = __half_as_ushort(__float2half(rs0));
        const unsigned int h1 = __half_as_ushort(__float2half(rs1));
        const unsigned int h2 = __half_as_ushort(__float2half(rs2));
        ((uint2*)epsv)[pos] =
            make_uint2(h0 | (h1 << 16), h2 | ((unsigned)ti << 16));
    }
}

// --- K5: per-node accumulation: TWO nodes/wave, asm-forced 8-wide loads ----
#define ACC16(Q, U)                                                           \
    do {                                                                      \
        const float x = (Q).x, y = (Q).y, z = (Q).z;                          \
        accA += (U).x;                                                        \
        v0 += (U).y * x; v1 += (U).y * y; v2 += (U).y * z;                    \
        const float _tx = (U).z * x, _ty = (U).z * y, _tz = (U).z * z;        \
        d00 += _tx * x; d01 += _tx * y; d02 += _tx * z;                       \
        d10 += _ty * x; d11 += _ty * y; d12 += _ty * z;                       \
        d20 += _tz * x; d21 += _tz * y; d22 += _tz * z;                       \
    } while (0)

template <bool P16>
__global__ void __launch_bounds__(64 * NPB, 4) k_nodes2(
    const void* __restrict__ epsv,
    const int* __restrict__ rowstart,
    const float* __restrict__ tabI,
    const int* __restrict__ flag,
    void* __restrict__ out, int N) {
    const int wave = threadIdx.x >> 6;
    const int lane = threadIdx.x & 63;
    const int n0 = (blockIdx.x * NPB + wave) * 2;
    const int a = lane & 31;
    const int half = lane >> 5;
    const int myn = n0 + half;
    const bool f32 = flag[0] != 0;
    const char* tabA = (const char*)tabI + a * 16;   // 16-B quad base

    int s0 = 0, s1 = 0;
    if (myn < N) { s0 = rowstart[myn]; s1 = rowstart[myn + 1]; }
    const int mylen = s1 - s0;
    const int lenA = __shfl(mylen, 0);
    const int lenB = __shfl(mylen, 32);
    const int minl = min(lenA, lenB);
    const int maxl = max(lenA, lenB);
    const int mclamp = max(mylen - 1, 0);

    float accA = 0.f, v0 = 0.f, v1 = 0.f, v2 = 0.f;
    float d00 = 0.f, d01 = 0.f, d02 = 0.f,
          d10 = 0.f, d11 = 0.f, d12 = 0.f,
          d20 = 0.f, d21 = 0.f, d22 = 0.f;

    if (P16) {
        int i = 0;
        // ---- main: unpredicated 8-wide batches up to minl ----
        for (; i + 8 <= minl; i += 8) {
            const char* pb = (const char*)epsv + (size_t)(s0 + i) * 16;
            f32x4 q0, q1, q2, q3, q4, q5, q6, q7;
            load8x16(pb, pb + 16, pb + 32, pb + 48,
                     pb + 64, pb + 80, pb + 96, pb + 112,
                     q0, q1, q2, q3, q4, q5, q6, q7);
            f32x4 u0, u1, u2, u3, u4, u5, u6, u7;
            load8x16(tabA + __float_as_int(q0.w), tabA + __float_as_int(q1.w),
                     tabA + __float_as_int(q2.w), tabA + __float_as_int(q3.w),
                     tabA + __float_as_int(q4.w), tabA + __float_as_int(q5.w),
                     tabA + __float_as_int(q6.w), tabA + __float_as_int(q7.w),
                     u0, u1, u2, u3, u4, u5, u6, u7);
            ACC16(q0, u0); ACC16(q1, u1); ACC16(q2, u2); ACC16(q3, u3);
            ACC16(q4, u4); ACC16(q5, u5); ACC16(q6, u6); ACC16(q7, u7);
        }
        // ---- remainder: predicated 8-wide batches up to maxl ----
        for (; i < maxl; i += 8) {
            float m0, m1, m2, m3, m4, m5, m6, m7;
#define TIDX(K) ((i + K) < mylen ? (i + K) : mclamp)
#define TPTR(K) ((const char*)epsv + (size_t)(s0 + TIDX(K)) * 16)
            m0 = (i + 0 < mylen) ? 1.f : 0.f;
            m1 = (i + 1 < mylen) ? 1.f : 0.f;
            m2 = (i + 2 < mylen) ? 1.f : 0.f;
            m3 = (i + 3 < mylen) ? 1.f : 0.f;
            m4 = (i + 4 < mylen) ? 1.f : 0.f;
            m5 = (i + 5 < mylen) ? 1.f : 0.f;
            m6 = (i + 6 < mylen) ? 1.f : 0.f;
            m7 = (i + 7 < mylen) ? 1.f : 0.f;
            f32x4 q0, q1, q2, q3, q4, q5, q6, q7;
            load8x16(TPTR(0), TPTR(1), TPTR(2), TPTR(3),
                     TPTR(4), TPTR(5), TPTR(6), TPTR(7),
                     q0, q1, q2, q3, q4, q5, q6, q7);
#undef TPTR
#undef TIDX
            f32x4 u0, u1, u2, u3, u4, u5, u6, u7;
            load8x16(tabA + __float_as_int(q0.w), tabA + __float_as_int(q1.w),
                     tabA + __float_as_int(q2.w), tabA + __float_as_int(q3.w),
                     tabA + __float_as_int(q4.w), tabA + __float_as_int(q5.w),
                     tabA + __float_as_int(q6.w), tabA + __float_as_int(q7.w),
                     u0, u1, u2, u3, u4, u5, u6, u7);
#define SAPX(K)                                                               \
            do { f32x4 uu = u##K; uu.x *= m##K; uu.y *= m##K; uu.z *= m##K;   \
                 ACC16(q##K, uu); } while (0)
            SAPX(0); SAPX(1); SAPX(2); SAPX(3);
            SAPX(4); SAPX(5); SAPX(6); SAPX(7);
#undef SAPX
        }
    } else {
        // ---- P8 fallback payload path (plain C, rarely used) ----
        for (int i = 0; i < maxl; i++) {
            if (i < mylen) {
                const u32x2 qh = *((const u32x2*)epsv + (s0 + i));
                const float x = __half2float(__ushort_as_half(
                    (unsigned short)(qh.x & 0xffffu)));
                const float y = __half2float(__ushort_as_half(
                    (unsigned short)(qh.x >> 16)));
                const float z = __half2float(__ushort_as_half(
                    (unsigned short)(qh.y & 0xffffu)));
                const TE t = *(const TE*)(tabA + (int)(qh.y >> 16) * ROWB);
                accA += t.r;
                v0 += t.v * x; v1 += t.v * y; v2 += t.v * z;
                const float _tx = t.d * x, _ty = t.d * y, _tz = t.d * z;
                d00 += _tx * x; d01 += _tx * y; d02 += _tx * z;
                d10 += _ty * x; d11 += _ty * y; d12 += _ty * z;
                d20 += _tz * x; d21 += _tz * y; d22 += _tz * z;
            }
        }
    }

    if (myn >= N) return;
    const size_t baseV = (size_t)N * 32;
    const size_t baseD = (size_t)N * 128;
    stf(out, (size_t)myn * 32 + a, accA, f32);
    const size_t vb = baseV + (size_t)myn * 96 + a * 3;
    stf(out, vb + 0, v0, f32);
    stf(out, vb + 1, v1, f32);
    stf(out, vb + 2, v2, f32);
    const size_t db = baseD + (size_t)myn * 288 + a * 9;
    stf(out, db + 0, d00, f32);
    stf(out, db + 1, d01, f32);
    stf(out, db + 2, d02, f32);
    stf(out, db + 3, d10, f32);
    stf(out, db + 4, d11, f32);
    stf(out, db + 5, d12, f32);
    stf(out, db + 6, d20, f32);
    stf(out, db + 7, d21, f32);
    stf(out, db + 8, d22, f32);
}

// --- fallback (ws too small for payload): perm + on-the-fly recompute ------
__global__ void __launch_bounds__(256) k_place_g(
        const int* __restrict__ src, const unsigned short* __restrict__ rank,
        const int* __restrict__ rowstart, int* __restrict__ perm, int E) {
    const int e = blockIdx.x * 256 + threadIdx.x;
    if (e < E) perm[rowstart[src[e]] + (int)rank[e]] = e;
}
__global__ void __launch_bounds__(256) k_nodes_fb(
    const int* __restrict__ perm, const void* __restrict__ r_ij,
    const int* __restrict__ rowstart, const float* __restrict__ tabI,
    const int* __restrict__ flag, void* __restrict__ out, int N) {
    const int wave = threadIdx.x >> 6;
    const int lane = threadIdx.x & 63;
    const int n = blockIdx.x * 4 + wave;
    if (n >= N) return;
    const int a = lane & 31;
    const bool hi = (lane >> 5) != 0;
    const bool f32 = flag[0] != 0;
    const int s0 = rowstart[n], s1 = rowstart[n + 1];
    float accR = 0.f, acc1 = 0.f, acc2 = 0.f, acc3 = 0.f,
          acc4 = 0.f, acc5 = 0.f, acc6 = 0.f;
    for (int idx = s0; idx < s1; idx++) {
        const int e = perm[idx];
        const float x0 = ldf(r_ij, 3 * e + 0, f32);
        const float y0 = ldf(r_ij, 3 * e + 1, f32);
        const float z0 = ldf(r_ij, 3 * e + 2, f32);
        const float d2 = x0 * x0 + y0 * y0 + z0 * z0;
        const float inv = rsqrtf(1.0f + 49.0f * d2);
        const float x = 7.0f * x0 * inv, y = 7.0f * y0 * inv, z = 7.0f * z0 * inv;
        const float u = fminf(sqrtf(d2), DMAX) * ((float)(TSIZE - 1) / DMAX);
        const int b = (int)(u + 0.5f) * ROWF + a * 4;   // padded row
        const float ra = tabI[b], rv = tabI[b + 1], rd = tabI[b + 2];
        const float b1 = (hi ? rd : rv) * (hi ? y : 1.0f);
        const float b2 = rd * (hi ? z : x);
        accR += ra;
        acc1 += b1 * x; acc2 += b1 * y; acc3 += b1 * z;
        acc4 += b2 * x; acc5 += b2 * y; acc6 += b2 * z;
    }
    const size_t baseV = (size_t)N * 32;
    const size_t baseD = (size_t)N * 128;
    if (!hi) {
        stf(out, (size_t)n * 32 + a, accR, f32);
        const size_t vb = baseV + (size_t)n * 96 + a * 3;
        stf(out, vb + 0, acc1, f32);
        stf(out, vb + 1, acc2, f32);
        stf(out, vb + 2, acc3, f32);
        const size_t db = baseD + (size_t)n * 288 + a * 9;
        stf(out, db + 0, acc4, f32);
        stf(out, db + 1, acc5, f32);
        stf(out, db + 2, acc6, f32);
    } else {
        const size_t db = baseD + (size_t)n * 288 + a * 9;
        stf(out, db + 3, acc1, f32);
        stf(out, db + 4, acc2, f32);
        stf(out, db + 5, acc3, f32);
        stf(out, db + 6, acc4, f32);
        stf(out, db + 7, acc5, f32);
        stf(out, db + 8, acc6, f32);
    }
}

extern "C" void kernel_launch(void* const* d_in, const int* in_sizes, int n_in,
                              void* d_out, int out_size, void* d_ws, size_t ws_size,
                              hipStream_t stream) {
    const void* r_ij     = d_in[0];
    const void* w_rad    = d_in[1];
    const void* b_rad    = d_in[2];
    const void* w_direct = d_in[3];
    const void* w1       = d_in[4];
    const void* b1       = d_in[5];
    const void* w2       = d_in[6];
    const void* b2       = d_in[7];
    const void* w3       = d_in[8];
    const void* b3       = d_in[9];
    const void* w_v      = d_in[10];
    const void* w_d      = d_in[11];
    const int* edges_src = (const int*)d_in[12];

    const int E = in_sizes[12];
    const int N = out_size / 416;   // 32 + 96 + 288 per node
    const int TB = TSIZE / EPB;
    const int ZB = (N + 255) / 256;                    // counts-zero blocks
    const int EB = (E + 255) / 256;                    // per-edge blocks
    const int nodeBlocks = (N + 2 * NPB - 1) / (2 * NPB);

    // tail: wcat + flag + tabI (4 MB) + counts N + rowstart N+1 + rank E u16
    const size_t tailBytes = ((size_t)W_TOT + 1) * 4 + (size_t)TSIZE * ROWF * 4
                           + ((size_t)N + N + 1) * 4 + (size_t)E * 2 + 64;
    const bool p16 = ws_size >= (size_t)E * 16 + tailBytes;
    const bool p8  = !p16 && ws_size >= (size_t)E * 8 + tailBytes;

    char* w = (char*)d_ws;
    if (p16 || p8) {
        const size_t slot = (size_t)E * (p16 ? 16 : 8);
        void* eps      = (void*)w;
        float* wcat    = (float*)(w + slot);
        int* flag      = (int*)(wcat + W_TOT);
        float* tabI    = (float*)(flag + 1);
        int* counts    = (int*)(tabI + (size_t)TSIZE * ROWF);
        int* rowstart  = counts + N;          // N+1
        unsigned short* rank = (unsigned short*)(rowstart + N + 1);   // E u16

        k_prep<<<12 + ZB, 256, 0, stream>>>(
            r_ij, w_rad, b_rad, w_direct, w1, b1, w2, b2, w3, b3, w_v, w_d,
            wcat, flag, counts, N);
        k_tabrank<<<TB + EB, 64 * EPB, 0, stream>>>(
            wcat, tabI, edges_src, counts, rank, E);
        k_scan<<<1, 1024, 0, stream>>>(counts, rowstart, N, E);
        if (p16) {
            k_place2<true><<<EB, 256, 0, stream>>>(
                edges_src, rank, rowstart, r_ij, flag, eps, E);
            k_nodes2<true><<<nodeBlocks, 64 * NPB, 0, stream>>>(
                eps, rowstart, tabI, flag, d_out, N);
        } else {
            k_place2<false><<<EB, 256, 0, stream>>>(
                edges_src, rank, rowstart, r_ij, flag, eps, E);
            k_nodes2<false><<<nodeBlocks, 64 * NPB, 0, stream>>>(
                eps, rowstart, tabI, flag, d_out, N);
        }
    } else {
        // fallback: perm-indexed nodes, on-the-fly recompute
        int* perm      = (int*)w;             // E
        float* wcat    = (float*)(w + (size_t)E * 4);
        int* flag      = (int*)(wcat + W_TOT);
        float* tabI    = (float*)(flag + 1);
        int* counts    = (int*)(tabI + (size_t)TSIZE * ROWF);
        int* rowstart  = counts + N;          // N+1
        unsigned short* rank = (unsigned short*)(rowstart + N + 1);   // E u16

        k_prep<<<12 + ZB, 256, 0, stream>>>(
            r_ij, w_rad, b_rad, w_direct, w1, b1, w2, b2, w3, b3, w_v, w_d,
            wcat, flag, counts, N);
        k_tabrank<<<TB + EB, 64 * EPB, 0, stream>>>(
            wcat, tabI, edges_src, counts, rank, E);
        k_scan<<<1, 1024, 0, stream>>>(counts, rowstart, N, E);
        k_place_g<<<EB, 256, 0, stream>>>(edges_src, rank, rowstart, perm, E);
        k_nodes_fb<<<(N + 3) / 4, 256, 0, stream>>>(
            perm, r_ij, rowstart, tabI, flag, d_out, N);
    }
}

// Round 15
// 203.203 us; speedup vs baseline: 1.2419x; 1.0419x over previous
//
#include <hip/hip_runtime.h>
#include <hip/hip_bf16.h>
#include <hip/hip_fp16.h>
#include <math.h>

// ---------------------------------------------------------------------------
// DisplacementTensors: rad = MLP(radial_encode(|r|)) depends only on |r| ->
// tabulate per-channel (ra,rv,rd,pad) 16-B quads (128 f32/row = 512 B,
// 8192 entries, 4 MB, L2/L3-resident).  CSR segment-sum WITHOUT atomics
// (Round-7 structure, best measured 201.0 us; launch-count experiments
// R19-R23 showed 8->6 dispatches = no change -> launch overhead falsified).
//   k_prep / k_table / k_hist / k_colscan / k_scan2 / k_place : CSR build
//   k_nodes2 : TWO nodes per wave.  R24/R25: counted-vmcnt software
//              pipeline inside the asm batches -- per 8 edges issue 8 table
//              loads + 8 NEXT-batch payload loads (16 outstanding),
//              vmcnt(8) -> table ready while payload flies, accumulate
//              (~400 cyc) hides payload latency, vmcnt(0) before reuse.
//              Waits are asm with "+v" ties so consumers can't be hoisted.
//              One exposed latency per 8 edges instead of two (R17 had
//              2x vmcnt(0) serial).  launch_bounds (256,3) for ~130 VGPR.
//              R25 fixes R24's pp-token bug: Q##0.w pasted 'pb' with the
//              pp-number '0.w' -> invalid token; now (Q##0).w.
// k_nodes2 ladder: R11 48.9 (JIT) -> R17 ~44 (asm 8-wide batches; NT stores
// were a 3x write-amplification trap; source-level ILP defeated by the
// pressure-minimizing scheduler -> asm blocks are the only reliable tool).
// Payload: float4 (rs0,rs1,rs2, table BYTE offset) when ws allows, else
// packed uint2 (f16 rs | u16 idx).  dtype (bf16/f32) runtime-detected.
// ---------------------------------------------------------------------------

#define TSIZE 8192
#define DMAX  2.0f           // RBF centers <=1, width 1/8 -> F const beyond ~2
#define EPB   4              // entries per block in k_table
#define HB    128            // edge chunks
#define TILE  10240          // node-tile size (40 KB LDS)
#define NPB   4              // waves per block in k_nodes2 (8 nodes/block)
#define ROWB  512            // table row bytes (32 ch x 16 B)
#define ROWF  128            // table row floats

// f32 concat-weight offsets (floats)
#define O_WRAD 0
#define O_BRAD 256
#define O_WDIR 288
#define O_W1   1312
#define O_B1   3360
#define O_W2   3424
#define O_B2   7520
#define O_W3   7584
#define O_B3   9632
#define O_WV   9664
#define O_WD   10688
#define W_TOT  11712

typedef float        f32x4 __attribute__((ext_vector_type(4)));
typedef unsigned int u32x2 __attribute__((ext_vector_type(2)));

struct TE { float r, v, d; };   // table triple view (12 of the 16 B)

__device__ __forceinline__ float lrelu(float x) { return x > 0.0f ? x : 0.1f * x; }

__device__ __forceinline__ float ldf(const void* p, int i, bool f32) {
    return f32 ? ((const float*)p)[i]
               : __uint_as_float(((unsigned int)((const unsigned short*)p)[i]) << 16);
}
__device__ __forceinline__ void stf(void* p, size_t i, float v, bool f32) {
    if (f32) ((float*)p)[i] = v;
    else     ((__hip_bfloat16*)p)[i] = __float2bfloat16(v);
}

__device__ __forceinline__ bool detect_f32(const void* r) {
    const unsigned short* p = (const unsigned short*)r;
    int bad = 0;
#pragma unroll 8
    for (int i = 0; i < 128; i++) {
        float v = __uint_as_float(((unsigned int)p[i]) << 16);
        bad |= (!isfinite(v) || fabsf(v) > 1e5f) ? 1 : 0;
    }
    return bad != 0;
}

// 8 independent 16-B loads in ONE asm block, WITH trailing vmcnt(0) (tail use)
__device__ __forceinline__ void load8x16(
    const void* p0, const void* p1, const void* p2, const void* p3,
    const void* p4, const void* p5, const void* p6, const void* p7,
    f32x4& q0, f32x4& q1, f32x4& q2, f32x4& q3,
    f32x4& q4, f32x4& q5, f32x4& q6, f32x4& q7) {
    asm volatile(
        "global_load_dwordx4 %0, %8, off\n\t"
        "global_load_dwordx4 %1, %9, off\n\t"
        "global_load_dwordx4 %2, %10, off\n\t"
        "global_load_dwordx4 %3, %11, off\n\t"
        "global_load_dwordx4 %4, %12, off\n\t"
        "global_load_dwordx4 %5, %13, off\n\t"
        "global_load_dwordx4 %6, %14, off\n\t"
        "global_load_dwordx4 %7, %15, off\n\t"
        "s_waitcnt vmcnt(0)"
        : "=&v"(q0), "=&v"(q1), "=&v"(q2), "=&v"(q3),
          "=&v"(q4), "=&v"(q5), "=&v"(q6), "=&v"(q7)
        : "v"(p0), "v"(p1), "v"(p2), "v"(p3),
          "v"(p4), "v"(p5), "v"(p6), "v"(p7));
}

// 8 independent 16-B loads, NO wait -- caller pairs with waitv8/waitv0.
__device__ __forceinline__ void load8x16_nw(
    const void* p0, const void* p1, const void* p2, const void* p3,
    const void* p4, const void* p5, const void* p6, const void* p7,
    f32x4& q0, f32x4& q1, f32x4& q2, f32x4& q3,
    f32x4& q4, f32x4& q5, f32x4& q6, f32x4& q7) {
    asm volatile(
        "global_load_dwordx4 %0, %8, off\n\t"
        "global_load_dwordx4 %1, %9, off\n\t"
        "global_load_dwordx4 %2, %10, off\n\t"
        "global_load_dwordx4 %3, %11, off\n\t"
        "global_load_dwordx4 %4, %12, off\n\t"
        "global_load_dwordx4 %5, %13, off\n\t"
        "global_load_dwordx4 %6, %14, off\n\t"
        "global_load_dwordx4 %7, %15, off"
        : "=&v"(q0), "=&v"(q1), "=&v"(q2), "=&v"(q3),
          "=&v"(q4), "=&v"(q5), "=&v"(q6), "=&v"(q7)
        : "v"(p0), "v"(p1), "v"(p2), "v"(p3),
          "v"(p4), "v"(p5), "v"(p6), "v"(p7));
}

// counted waits with "+v" ties: consumers of r* are SSA-ordered after the
// wait, so the compiler cannot hoist them above it (rule-18-proof).
__device__ __forceinline__ void waitv8(
    f32x4& r0, f32x4& r1, f32x4& r2, f32x4& r3,
    f32x4& r4, f32x4& r5, f32x4& r6, f32x4& r7) {
    asm volatile("s_waitcnt vmcnt(8)"
        : "+v"(r0), "+v"(r1), "+v"(r2), "+v"(r3),
          "+v"(r4), "+v"(r5), "+v"(r6), "+v"(r7));
}
__device__ __forceinline__ void waitv0(
    f32x4& r0, f32x4& r1, f32x4& r2, f32x4& r3,
    f32x4& r4, f32x4& r5, f32x4& r6, f32x4& r7) {
    asm volatile("s_waitcnt vmcnt(0)"
        : "+v"(r0), "+v"(r1), "+v"(r2), "+v"(r3),
          "+v"(r4), "+v"(r5), "+v"(r6), "+v"(r7));
}

// --- prep: flag store | weight->f32 concat | (fallback) zero counts --------
__global__ void k_prep(const void* __restrict__ r_ij,
                       const void* w_rad, const void* b_rad, const void* w_direct,
                       const void* w1, const void* b1, const void* w2, const void* b2,
                       const void* w3, const void* b3, const void* w_v, const void* w_d,
                       float* __restrict__ wcat, int* __restrict__ flag,
                       int* __restrict__ counts, int N) {
    const int b = blockIdx.x;
    if (b == 0) {
        if (threadIdx.x == 0) flag[0] = detect_f32(r_ij) ? 1 : 0;
    } else if (b <= 11) {
        const bool f32 = detect_f32(r_ij);
        const void* src; int cnt; int off;
        switch (b) {
            case 1:  src = w_rad;    cnt = 256;  off = O_WRAD; break;
            case 2:  src = b_rad;    cnt = 32;   off = O_BRAD; break;
            case 3:  src = w_direct; cnt = 1024; off = O_WDIR; break;
            case 4:  src = w1;       cnt = 2048; off = O_W1;   break;
            case 5:  src = b1;       cnt = 64;   off = O_B1;   break;
            case 6:  src = w2;       cnt = 4096; off = O_W2;   break;
            case 7:  src = b2;       cnt = 64;   off = O_B2;   break;
            case 8:  src = w3;       cnt = 2048; off = O_W3;   break;
            case 9:  src = b3;       cnt = 32;   off = O_B3;   break;
            case 10: src = w_v;      cnt = 1024; off = O_WV;   break;
            default: src = w_d;      cnt = 1024; off = O_WD;   break;
        }
        for (int i = threadIdx.x; i < cnt; i += blockDim.x)
            wcat[off + i] = ldf(src, i, f32);
    } else if (counts) {
        int i = (b - 12) * blockDim.x + threadIdx.x;
        if (i < N) counts[i] = 0;
    }
}

// --- LUT build: 4 entries/block, wave = entry, lane = neuron ---------------
__global__ void __launch_bounds__(64 * EPB) k_table(const float* __restrict__ wcat,
                                                    float* __restrict__ tabI) {
    __shared__ float Lh[EPB][32], Lt1[EPB][64], Lt2[EPB][64], Lrad[EPB][32];

    const int s = threadIdx.x >> 6;
    const int j = threadIdx.x & 63;
    const int e = blockIdx.x * EPB + s;
    const float d = (float)e * (DMAX / (float)(TSIZE - 1));

    float enc[8];
#pragma unroll
    for (int k = 0; k < 8; k++) {
        float t = (d - (float)k * (1.0f / 7.0f)) * 8.0f;
        enc[k] = expf(-t * t);
    }

    if (j < 32) {
        float hv = wcat[O_BRAD + j];
#pragma unroll
        for (int k = 0; k < 8; k++) hv = fmaf(enc[k], wcat[O_WRAD + k * 32 + j], hv);
        Lh[s][j] = hv;
    }
    __syncthreads();

    {
        float v = wcat[O_B1 + j];
#pragma unroll
        for (int i = 0; i < 32; i++) v = fmaf(Lh[s][i], wcat[O_W1 + i * 64 + j], v);
        Lt1[s][j] = lrelu(v);
    }
    __syncthreads();

    {
        float v = wcat[O_B2 + j];
#pragma unroll
        for (int i = 0; i < 64; i++) v = fmaf(Lt1[s][i], wcat[O_W2 + i * 64 + j], v);
        Lt2[s][j] = lrelu(v);
    }
    __syncthreads();

    if (j < 32) {
        float v = wcat[O_B3 + j];
#pragma unroll
        for (int i = 0; i < 64; i++) v = fmaf(Lt2[s][i], wcat[O_W3 + i * 32 + j], v);
#pragma unroll
        for (int i = 0; i < 32; i++) v = fmaf(Lh[s][i], wcat[O_WDIR + i * 32 + j], v);
        Lrad[s][j] = v;
    }
    __syncthreads();

    if (j < 32) {
        float sv = 0.0f, sd = 0.0f;
#pragma unroll
        for (int i = 0; i < 32; i++) {
            float ri = Lrad[s][i];
            sv = fmaf(ri, wcat[O_WV + i * 32 + j], sv);
            sd = fmaf(ri, wcat[O_WD + i * 32 + j], sd);
        }
        float* row = tabI + (size_t)e * ROWF + j * 4;
        row[0] = Lrad[s][j];
        row[1] = sv;
        row[2] = sd;
        row[3] = 0.0f;
    }
}

// --- CSR pass 1: per-(chunk,tile) LDS histogram -> u16 cnt -----------------
__global__ void __launch_bounds__(256) k_hist(const int* __restrict__ src, int E,
                                              int chunk,
                                              unsigned short* __restrict__ cnt,
                                              int N) {
    __shared__ int lcnt[TILE];
    const int b = blockIdx.x % HB;
    const int t = blockIdx.x / HB;
    const int lo = b * chunk;
    const int hi = min(lo + chunk, E);
    const int t0 = t * TILE;
    const int tl = min(TILE, N - t0);

    for (int i = threadIdx.x; i < tl; i += 256) lcnt[i] = 0;
    __syncthreads();
    for (int e = lo + threadIdx.x; e < hi; e += 256) {
        const int s = src[e] - t0;
        if ((unsigned)s < (unsigned)tl) atomicAdd(&lcnt[s], 1);
    }
    __syncthreads();
    unsigned short* out = cnt + (size_t)(t * HB + b) * TILE;
    for (int i = threadIdx.x; i < tl; i += 256)
        out[i] = (unsigned short)lcnt[i];
}

// --- CSR pass 2: per-node prefix over chunks; coarse sum per 64-node block -
__global__ void __launch_bounds__(64) k_colscan(unsigned short* __restrict__ cnt,
                                                int* __restrict__ tot,
                                                int* __restrict__ coarse, int N) {
    const int lane = threadIdx.x;
    const int n = blockIdx.x * 64 + lane;
    int run = 0;
    if (n < N) {
        const int t = n / TILE;
        const int nl = n % TILE;
        unsigned short* col = cnt + (size_t)(t * HB) * TILE + nl;
#pragma unroll 4
        for (int b = 0; b < HB; b++) {
            int c = col[(size_t)b * TILE];
            col[(size_t)b * TILE] = (unsigned short)run;
            run += c;
        }
        tot[n] = run;
    }
    int s = run;
    for (int off = 32; off > 0; off >>= 1) s += __shfl_down(s, off);
    if (lane == 0) coarse[blockIdx.x] = s;
}

// --- CSR pass 3: rowstart; coarse prefix summed cooperatively --------------
__global__ void __launch_bounds__(64) k_scan2(const int* __restrict__ tot,
                                              const int* __restrict__ coarse,
                                              int* __restrict__ rowstart, int N) {
    const int lane = threadIdx.x;
    const int b = blockIdx.x;
    int cp = 0;
    for (int j = lane; j < b; j += 64) cp += coarse[j];
    for (int off = 32; off > 0; off >>= 1) cp += __shfl_down(cp, off);
    const int cpre = __shfl(cp, 0);

    const int n = b * 64 + lane;
    const int v = (n < N) ? tot[n] : 0;
    int inc = v;
    for (int off = 1; off < 64; off <<= 1) {
        int y = __shfl_up(inc, off);
        if (lane >= off) inc += y;
    }
    if (n < N) rowstart[n] = cpre + inc - v;
    if (n == N - 1) rowstart[N] = cpre + inc;
}

// --- CSR pass 4: place payload via LDS cursor ------------------------------
template <bool P16>
__global__ void __launch_bounds__(256) k_place(
        const int* __restrict__ src, int E, int chunk,
        const unsigned short* __restrict__ cnt, const int* __restrict__ rowstart,
        const void* __restrict__ r_ij, const int* __restrict__ flag,
        void* __restrict__ epsv, int N) {
    __shared__ int cur[TILE];
    const int b = blockIdx.x % HB;
    const int t = blockIdx.x / HB;
    const int lo = b * chunk;
    const int hi = min(lo + chunk, E);
    const int t0 = t * TILE;
    const int tl = min(TILE, N - t0);
    const bool f32 = flag[0] != 0;

    const unsigned short* base = cnt + (size_t)(t * HB + b) * TILE;
    for (int i = threadIdx.x; i < tl; i += 256)
        cur[i] = rowstart[t0 + i] + (int)base[i];
    __syncthreads();
    for (int e = lo + threadIdx.x; e < hi; e += 256) {
        const int s = src[e] - t0;
        if ((unsigned)s < (unsigned)tl) {
            const int pos = atomicAdd(&cur[s], 1);
            const float x = ldf(r_ij, 3 * e + 0, f32);
            const float y = ldf(r_ij, 3 * e + 1, f32);
            const float z = ldf(r_ij, 3 * e + 2, f32);
            const float d2 = x * x + y * y + z * z;
            const float inv = rsqrtf(1.0f + 49.0f * d2);  // tens_sigmoid(7r)
            const float u = fminf(sqrtf(d2), DMAX) * ((float)(TSIZE - 1) / DMAX);
            const int ti = (int)(u + 0.5f);               // nearest, <= TSIZE-1
            const float rs0 = 7.0f * x * inv, rs1 = 7.0f * y * inv,
                        rs2 = 7.0f * z * inv;
            if (P16) {
                ((float4*)epsv)[pos] =
                    make_float4(rs0, rs1, rs2, __int_as_float(ti * ROWB));
            } else {
                const unsigned int h0 = __half_as_ushort(__float2half(rs0));
                const unsigned int h1 = __half_as_ushort(__float2half(rs1));
                const unsigned int h2 = __half_as_ushort(__float2half(rs2));
                ((uint2*)epsv)[pos] =
                    make_uint2(h0 | (h1 << 16), h2 | ((unsigned)ti << 16));
            }
        }
    }
}

// --- per-node accumulation: TWO nodes per wave, counted-vmcnt pipeline -----
#define ACC16(Q, U)                                                           \
    do {                                                                      \
        const float x = (Q).x, y = (Q).y, z = (Q).z;                          \
        accA += (U).x;                                                        \
        v0 += (U).y * x; v1 += (U).y * y; v2 += (U).y * z;                    \
        const float _tx = (U).z * x, _ty = (U).z * y, _tz = (U).z * z;        \
        d00 += _tx * x; d01 += _tx * y; d02 += _tx * z;                       \
        d10 += _ty * x; d11 += _ty * y; d12 += _ty * z;                       \
        d20 += _tz * x; d21 += _tz * y; d22 += _tz * z;                       \
    } while (0)

#define P8ARGS(R) R##0, R##1, R##2, R##3, R##4, R##5, R##6, R##7
#define LOADP_NW(R, IDX)                                                      \
    do { const char* _pp = (const char*)epsv + (size_t)(IDX) * 16;            \
         load8x16_nw(_pp, _pp + 16, _pp + 32, _pp + 48,                       \
                     _pp + 64, _pp + 80, _pp + 96, _pp + 112, P8ARGS(R));     \
    } while (0)
#define LOADT_NW(R, Q)                                                        \
    load8x16_nw(tabA + __float_as_int((Q##0).w),                              \
                tabA + __float_as_int((Q##1).w),                              \
                tabA + __float_as_int((Q##2).w),                              \
                tabA + __float_as_int((Q##3).w),                              \
                tabA + __float_as_int((Q##4).w),                              \
                tabA + __float_as_int((Q##5).w),                              \
                tabA + __float_as_int((Q##6).w),                              \
                tabA + __float_as_int((Q##7).w),                              \
                P8ARGS(R))
#define ACCB(Q, T)                                                            \
    do { ACC16(Q##0, T##0); ACC16(Q##1, T##1); ACC16(Q##2, T##2);             \
         ACC16(Q##3, T##3); ACC16(Q##4, T##4); ACC16(Q##5, T##5);             \
         ACC16(Q##6, T##6); ACC16(Q##7, T##7); } while (0)

template <bool P16>
__global__ void __launch_bounds__(64 * NPB, 3) k_nodes2(
    const void* __restrict__ epsv,
    const int* __restrict__ rowstart,
    const float* __restrict__ tabI,
    const int* __restrict__ flag,
    void* __restrict__ out, int N) {
    const int wave = threadIdx.x >> 6;
    const int lane = threadIdx.x & 63;
    const int n0 = (blockIdx.x * NPB + wave) * 2;
    const int a = lane & 31;
    const int half = lane >> 5;
    const int myn = n0 + half;
    const bool f32 = flag[0] != 0;
    const char* tabA = (const char*)tabI + a * 16;   // 16-B quad base

    int s0 = 0, s1 = 0;
    if (myn < N) { s0 = rowstart[myn]; s1 = rowstart[myn + 1]; }
    const int mylen = s1 - s0;
    const int lenA = __shfl(mylen, 0);
    const int lenB = __shfl(mylen, 32);
    const int minl = min(lenA, lenB);
    const int maxl = max(lenA, lenB);
    const int mclamp = max(mylen - 1, 0);

    float accA = 0.f, v0 = 0.f, v1 = 0.f, v2 = 0.f;
    float d00 = 0.f, d01 = 0.f, d02 = 0.f,
          d10 = 0.f, d11 = 0.f, d12 = 0.f,
          d20 = 0.f, d21 = 0.f, d22 = 0.f;

    if (P16) {
        int i = 0;
        if (minl >= 8) {
            f32x4 pa0, pa1, pa2, pa3, pa4, pa5, pa6, pa7;
            f32x4 pb0, pb1, pb2, pb3, pb4, pb5, pb6, pb7;
            f32x4 tt0, tt1, tt2, tt3, tt4, tt5, tt6, tt7;
            LOADP_NW(pa, s0);
            waitv0(P8ARGS(pa));
            // main: 16 edges/iter; T(k) + P(k+1) in flight together,
            // vmcnt(8) frees T while P flies under the accumulate.
            for (; i + 24 <= minl; i += 16) {
                LOADT_NW(tt, pa);
                LOADP_NW(pb, s0 + i + 8);
                waitv8(P8ARGS(tt));
                ACCB(pa, tt);
                waitv0(P8ARGS(pb));
                LOADT_NW(tt, pb);
                LOADP_NW(pa, s0 + i + 16);
                waitv8(P8ARGS(tt));
                ACCB(pb, tt);
                waitv0(P8ARGS(pa));
            }
            if (i + 16 <= minl) {          // two batches left
                LOADT_NW(tt, pa);
                LOADP_NW(pb, s0 + i + 8);
                waitv8(P8ARGS(tt));
                ACCB(pa, tt);
                waitv0(P8ARGS(pb));
                LOADT_NW(tt, pb);
                waitv0(P8ARGS(tt));
                ACCB(pb, tt);
                i += 16;
            } else {                        // one batch left
                LOADT_NW(tt, pa);
                waitv0(P8ARGS(tt));
                ACCB(pa, tt);
                i += 8;
            }
        }
        // ---- remainder: predicated 8-wide batches up to maxl ----
        for (; i < maxl; i += 8) {
            float m0, m1, m2, m3, m4, m5, m6, m7;
#define TIDX(K) ((i + K) < mylen ? (i + K) : mclamp)
#define TPTR(K) ((const char*)epsv + (size_t)(s0 + TIDX(K)) * 16)
            m0 = (i + 0 < mylen) ? 1.f : 0.f;
            m1 = (i + 1 < mylen) ? 1.f : 0.f;
            m2 = (i + 2 < mylen) ? 1.f : 0.f;
            m3 = (i + 3 < mylen) ? 1.f : 0.f;
            m4 = (i + 4 < mylen) ? 1.f : 0.f;
            m5 = (i + 5 < mylen) ? 1.f : 0.f;
            m6 = (i + 6 < mylen) ? 1.f : 0.f;
            m7 = (i + 7 < mylen) ? 1.f : 0.f;
            f32x4 q0, q1, q2, q3, q4, q5, q6, q7;
            load8x16(TPTR(0), TPTR(1), TPTR(2), TPTR(3),
                     TPTR(4), TPTR(5), TPTR(6), TPTR(7),
                     q0, q1, q2, q3, q4, q5, q6, q7);
#undef TPTR
#undef TIDX
            f32x4 u0, u1, u2, u3, u4, u5, u6, u7;
            load8x16(tabA + __float_as_int(q0.w), tabA + __float_as_int(q1.w),
                     tabA + __float_as_int(q2.w), tabA + __float_as_int(q3.w),
                     tabA + __float_as_int(q4.w), tabA + __float_as_int(q5.w),
                     tabA + __float_as_int(q6.w), tabA + __float_as_int(q7.w),
                     u0, u1, u2, u3, u4, u5, u6, u7);
#define SAPX(K)                                                               \
            do { f32x4 uu = u##K; uu.x *= m##K; uu.y *= m##K; uu.z *= m##K;   \
                 ACC16(q##K, uu); } while (0)
            SAPX(0); SAPX(1); SAPX(2); SAPX(3);
            SAPX(4); SAPX(5); SAPX(6); SAPX(7);
#undef SAPX
        }
    } else {
        // ---- P8 fallback payload path (plain C, rarely used) ----
        for (int i = 0; i < maxl; i++) {
            if (i < mylen) {
                const u32x2 qh = *((const u32x2*)epsv + (s0 + i));
                const float x = __half2float(__ushort_as_half(
                    (unsigned short)(qh.x & 0xffffu)));
                const float y = __half2float(__ushort_as_half(
                    (unsigned short)(qh.x >> 16)));
                const float z = __half2float(__ushort_as_half(
                    (unsigned short)(qh.y & 0xffffu)));
                const TE t = *(const TE*)(tabA + (int)(qh.y >> 16) * ROWB);
                accA += t.r;
                v0 += t.v * x; v1 += t.v * y; v2 += t.v * z;
                const float _tx = t.d * x, _ty = t.d * y, _tz = t.d * z;
                d00 += _tx * x; d01 += _tx * y; d02 += _tx * z;
                d10 += _ty * x; d11 += _ty * y; d12 += _ty * z;
                d20 += _tz * x; d21 += _tz * y; d22 += _tz * z;
            }
        }
    }

    if (myn >= N) return;
    const size_t baseV = (size_t)N * 32;
    const size_t baseD = (size_t)N * 128;
    stf(out, (size_t)myn * 32 + a, accA, f32);
    const size_t vb = baseV + (size_t)myn * 96 + a * 3;
    stf(out, vb + 0, v0, f32);
    stf(out, vb + 1, v1, f32);
    stf(out, vb + 2, v2, f32);
    const size_t db = baseD + (size_t)myn * 288 + a * 9;
    stf(out, db + 0, d00, f32);
    stf(out, db + 1, d01, f32);
    stf(out, db + 2, d02, f32);
    stf(out, db + 3, d10, f32);
    stf(out, db + 4, d11, f32);
    stf(out, db + 5, d12, f32);
    stf(out, db + 6, d20, f32);
    stf(out, db + 7, d21, f32);
    stf(out, db + 8, d22, f32);
}

// --- fallback CSR (global atomics) + perm-based nodes ----------------------
__global__ void k_rank_g(const int* __restrict__ src, int* __restrict__ counts,
                         int* __restrict__ rank, int E) {
    int e = blockIdx.x * blockDim.x + threadIdx.x;
    if (e < E) rank[e] = atomicAdd(&counts[src[e]], 1);
}
__global__ void k_scan_g(const int* __restrict__ counts, int* __restrict__ rowstart,
                         int N, int E) {
    __shared__ int part[1024];
    const int t = threadIdx.x;
    const int CH = (N + 1023) / 1024;
    const int lo = t * CH;
    const int hi = min(lo + CH, N);
    int s = 0;
    for (int i = lo; i < hi; i++) s += counts[i];
    part[t] = s;
    __syncthreads();
    for (int off = 1; off < 1024; off <<= 1) {
        int v = part[t];
        int w = (t >= off) ? part[t - off] : 0;
        __syncthreads();
        part[t] = v + w;
        __syncthreads();
    }
    int run = (t == 0) ? 0 : part[t - 1];
    for (int i = lo; i < hi; i++) { rowstart[i] = run; run += counts[i]; }
    if (t == 0) rowstart[N] = E;
}
__global__ void k_place_g(const int* __restrict__ src, const int* __restrict__ rank,
                          const int* __restrict__ rowstart,
                          int* __restrict__ perm, int E) {
    int e = blockIdx.x * blockDim.x + threadIdx.x;
    if (e < E) perm[rowstart[src[e]] + rank[e]] = e;
}
__global__ void __launch_bounds__(256) k_nodes_fb(
    const int* __restrict__ perm, const void* __restrict__ r_ij,
    const int* __restrict__ rowstart, const float* __restrict__ tabI,
    const int* __restrict__ flag, void* __restrict__ out, int N) {
    const int wave = threadIdx.x >> 6;
    const int lane = threadIdx.x & 63;
    const int n = blockIdx.x * 4 + wave;
    if (n >= N) return;
    const int a = lane & 31;
    const bool hi = (lane >> 5) != 0;
    const bool f32 = flag[0] != 0;
    const int s0 = rowstart[n], s1 = rowstart[n + 1];
    float accR = 0.f, acc1 = 0.f, acc2 = 0.f, acc3 = 0.f,
          acc4 = 0.f, acc5 = 0.f, acc6 = 0.f;
    for (int idx = s0; idx < s1; idx++) {
        const int e = perm[idx];
        const float x0 = ldf(r_ij, 3 * e + 0, f32);
        const float y0 = ldf(r_ij, 3 * e + 1, f32);
        const float z0 = ldf(r_ij, 3 * e + 2, f32);
        const float d2 = x0 * x0 + y0 * y0 + z0 * z0;
        const float inv = rsqrtf(1.0f + 49.0f * d2);
        const float x = 7.0f * x0 * inv, y = 7.0f * y0 * inv, z = 7.0f * z0 * inv;
        const float u = fminf(sqrtf(d2), DMAX) * ((float)(TSIZE - 1) / DMAX);
        const int b = (int)(u + 0.5f) * ROWF + a * 4;   // padded row
        const float ra = tabI[b], rv = tabI[b + 1], rd = tabI[b + 2];
        const float b1 = (hi ? rd : rv) * (hi ? y : 1.0f);
        const float b2 = rd * (hi ? z : x);
        accR += ra;
        acc1 += b1 * x; acc2 += b1 * y; acc3 += b1 * z;
        acc4 += b2 * x; acc5 += b2 * y; acc6 += b2 * z;
    }
    const size_t baseV = (size_t)N * 32;
    const size_t baseD = (size_t)N * 128;
    if (!hi) {
        stf(out, (size_t)n * 32 + a, accR, f32);
        const size_t vb = baseV + (size_t)n * 96 + a * 3;
        stf(out, vb + 0, acc1, f32);
        stf(out, vb + 1, acc2, f32);
        stf(out, vb + 2, acc3, f32);
        const size_t db = baseD + (size_t)n * 288 + a * 9;
        stf(out, db + 0, acc4, f32);
        stf(out, db + 1, acc5, f32);
        stf(out, db + 2, acc6, f32);
    } else {
        const size_t db = baseD + (size_t)n * 288 + a * 9;
        stf(out, db + 3, acc1, f32);
        stf(out, db + 4, acc2, f32);
        stf(out, db + 5, acc3, f32);
        stf(out, db + 6, acc4, f32);
        stf(out, db + 7, acc5, f32);
        stf(out, db + 8, acc6, f32);
    }
}

extern "C" void kernel_launch(void* const* d_in, const int* in_sizes, int n_in,
                              void* d_out, int out_size, void* d_ws, size_t ws_size,
                              hipStream_t stream) {
    const void* r_ij     = d_in[0];
    const void* w_rad    = d_in[1];
    const void* b_rad    = d_in[2];
    const void* w_direct = d_in[3];
    const void* w1       = d_in[4];
    const void* b1       = d_in[5];
    const void* w2       = d_in[6];
    const void* b2       = d_in[7];
    const void* w3       = d_in[8];
    const void* b3       = d_in[9];
    const void* w_v      = d_in[10];
    const void* w_d      = d_in[11];
    const int* edges_src = (const int*)d_in[12];

    const int E = in_sizes[12];
    const int N = out_size / 416;   // 32 + 96 + 288 per node
    const int chunk = (E + HB - 1) / HB;
    const int ntiles = (N + TILE - 1) / TILE;
    const int NB = (N + 63) / 64;

    const size_t cntBytes  = (size_t)ntiles * HB * TILE * 2;
    const size_t tailBytes = ((size_t)W_TOT + 4) * 4 + (size_t)TSIZE * ROWF * 4
                           + cntBytes + ((size_t)N + NB + N + 1) * 4;
    const bool p16 = ws_size >= (size_t)E * 16 + tailBytes + 64;
    const bool p8  = !p16 && ws_size >= (size_t)E * 8 + tailBytes + 64;

    char* w = (char*)d_ws;
    if (p16 || p8) {
        const size_t slot = (size_t)E * (p16 ? 16 : 8);
        void* eps     = (void*)w;
        float* wcat   = (float*)(w + slot);
        int* flag     = (int*)(wcat + W_TOT);
        float* tabI   = (float*)(flag + 4);
        unsigned short* cnt = (unsigned short*)(tabI + (size_t)TSIZE * ROWF);
        int* tot      = (int*)((char*)cnt + cntBytes);
        int* coarse   = tot + N;              // NB entries
        int* rowstart = coarse + NB;          // N+1

        const int nodeBlocks = (N + 2 * NPB - 1) / (2 * NPB);
        k_prep<<<12, 256, 0, stream>>>(
            r_ij, w_rad, b_rad, w_direct, w1, b1, w2, b2, w3, b3, w_v, w_d,
            wcat, flag, nullptr, N);
        k_table<<<TSIZE / EPB, 64 * EPB, 0, stream>>>(wcat, tabI);
        k_hist<<<HB * ntiles, 256, 0, stream>>>(edges_src, E, chunk, cnt, N);
        k_colscan<<<NB, 64, 0, stream>>>(cnt, tot, coarse, N);
        k_scan2<<<NB, 64, 0, stream>>>(tot, coarse, rowstart, N);
        if (p16) {
            k_place<true><<<HB * ntiles, 256, 0, stream>>>(
                edges_src, E, chunk, cnt, rowstart, r_ij, flag, eps, N);
            k_nodes2<true><<<nodeBlocks, 64 * NPB, 0, stream>>>(
                eps, rowstart, tabI, flag, d_out, N);
        } else {
            k_place<false><<<HB * ntiles, 256, 0, stream>>>(
                edges_src, E, chunk, cnt, rowstart, r_ij, flag, eps, N);
            k_nodes2<false><<<nodeBlocks, 64 * NPB, 0, stream>>>(
                eps, rowstart, tabI, flag, d_out, N);
        }
    } else {
        // fallback: global-atomic rank path, perm-indexed nodes
        int* perm     = (int*)w;              // E
        float* wcat   = (float*)(w + (size_t)E * 4);
        int* flag     = (int*)(wcat + W_TOT);
        float* tabI   = (float*)(flag + 4);
        int* counts   = (int*)(tabI + (size_t)TSIZE * ROWF);
        int* rowstart = counts + N;           // N+1
        int* rank     = rowstart + N + 1;     // E

        k_prep<<<12 + (N + 255) / 256, 256, 0, stream>>>(
            r_ij, w_rad, b_rad, w_direct, w1, b1, w2, b2, w3, b3, w_v, w_d,
            wcat, flag, counts, N);
        k_table<<<TSIZE / EPB, 64 * EPB, 0, stream>>>(wcat, tabI);
        k_rank_g<<<(E + 255) / 256, 256, 0, stream>>>(edges_src, counts, rank, E);
        k_scan_g<<<1, 1024, 0, stream>>>(counts, rowstart, N, E);
        k_place_g<<<(E + 255) / 256, 256, 0, stream>>>(edges_src, rank, rowstart,
                                                       perm, E);
        k_nodes_fb<<<(N + 3) / 4, 256, 0, stream>>>(
            perm, r_ij, rowstart, tabI, flag, d_out, N);
    }
}

// Round 16
// 191.841 us; speedup vs baseline: 1.3155x; 1.0592x over previous
//
#include <hip/hip_runtime.h>
#include <hip/hip_bf16.h>
#include <hip/hip_fp16.h>
#include <math.h>

// ---------------------------------------------------------------------------
// DisplacementTensors: rad = MLP(radial_encode(|r|)) depends only on |r| ->
// tabulate per-channel (ra,rv,rd,pad) 16-B quads (128 f32/row = 512 B,
// 8192 entries, 4 MB, L2/L3-resident).
// R26: 6 all-parallel dispatches (R23's launch-cut retried WITHOUT its
// single-block-scan confound; R7's k_hist/k_place ran on only 256 blocks):
//   k_prep    : flag + weight->f32 wcat + zero counts        (91 blocks)
//   k_tabrank : table build from wcat (2048 blks) + rank atomics (2500 blks)
//   k_sum     : coarse[b] = sum counts[64b..64b+63]          (313 blocks)
//   k_scan2c  : cooperative coarse prefix -> rowstart        (313 blocks)
//   k_place2  : pos = rowstart[src]+rank; payload write      (2500 blocks)
//   k_nodes2  : TWO nodes/wave, asm counted-vmcnt pipeline (R25, proven):
//               per 8 edges issue 8 table + 8 next-payload loads (16
//               outstanding), vmcnt(8) -> accumulate hides payload flight.
// Ledger: NT stores = 3x write amp (R12); source ILP defeated by scheduler
// (R14-R16); asm batches only reliable tool (R17); bf16 per-FMA weight reads
// = 10x k_table regression (R22); 1-block scan = ~25 us latency (R23).
// Payload order within a node nondeterministic (atomic rank) -- only
// permutes fp32 accumulation order; bf16 output tolerance dwarfs it.
// ---------------------------------------------------------------------------

#define TSIZE 8192
#define DMAX  2.0f           // RBF centers <=1, width 1/8 -> F const beyond ~2
#define EPB   4              // entries per block in k_tabrank table section
#define NPB   4              // waves per block in k_nodes2 (8 nodes/block)
#define ROWB  512            // table row bytes (32 ch x 16 B)
#define ROWF  128            // table row floats

// f32 concat-weight offsets (floats)
#define O_WRAD 0
#define O_BRAD 256
#define O_WDIR 288
#define O_W1   1312
#define O_B1   3360
#define O_W2   3424
#define O_B2   7520
#define O_W3   7584
#define O_B3   9632
#define O_WV   9664
#define O_WD   10688
#define W_TOT  11712

typedef float        f32x4 __attribute__((ext_vector_type(4)));
typedef unsigned int u32x2 __attribute__((ext_vector_type(2)));

struct TE { float r, v, d; };   // table triple view (12 of the 16 B)

__device__ __forceinline__ float lrelu(float x) { return x > 0.0f ? x : 0.1f * x; }

__device__ __forceinline__ float ldf(const void* p, int i, bool f32) {
    return f32 ? ((const float*)p)[i]
               : __uint_as_float(((unsigned int)((const unsigned short*)p)[i]) << 16);
}
__device__ __forceinline__ void stf(void* p, size_t i, float v, bool f32) {
    if (f32) ((float*)p)[i] = v;
    else     ((__hip_bfloat16*)p)[i] = __float2bfloat16(v);
}

__device__ __forceinline__ bool detect_f32(const void* r) {
    const unsigned short* p = (const unsigned short*)r;
    int bad = 0;
#pragma unroll 8
    for (int i = 0; i < 128; i++) {
        float v = __uint_as_float(((unsigned int)p[i]) << 16);
        bad |= (!isfinite(v) || fabsf(v) > 1e5f) ? 1 : 0;
    }
    return bad != 0;
}

// 8 independent 16-B loads in ONE asm block, WITH trailing vmcnt(0)
__device__ __forceinline__ void load8x16(
    const void* p0, const void* p1, const void* p2, const void* p3,
    const void* p4, const void* p5, const void* p6, const void* p7,
    f32x4& q0, f32x4& q1, f32x4& q2, f32x4& q3,
    f32x4& q4, f32x4& q5, f32x4& q6, f32x4& q7) {
    asm volatile(
        "global_load_dwordx4 %0, %8, off\n\t"
        "global_load_dwordx4 %1, %9, off\n\t"
        "global_load_dwordx4 %2, %10, off\n\t"
        "global_load_dwordx4 %3, %11, off\n\t"
        "global_load_dwordx4 %4, %12, off\n\t"
        "global_load_dwordx4 %5, %13, off\n\t"
        "global_load_dwordx4 %6, %14, off\n\t"
        "global_load_dwordx4 %7, %15, off\n\t"
        "s_waitcnt vmcnt(0)"
        : "=&v"(q0), "=&v"(q1), "=&v"(q2), "=&v"(q3),
          "=&v"(q4), "=&v"(q5), "=&v"(q6), "=&v"(q7)
        : "v"(p0), "v"(p1), "v"(p2), "v"(p3),
          "v"(p4), "v"(p5), "v"(p6), "v"(p7));
}

// 8 independent 16-B loads, NO wait -- caller pairs with waitv8/waitv0.
__device__ __forceinline__ void load8x16_nw(
    const void* p0, const void* p1, const void* p2, const void* p3,
    const void* p4, const void* p5, const void* p6, const void* p7,
    f32x4& q0, f32x4& q1, f32x4& q2, f32x4& q3,
    f32x4& q4, f32x4& q5, f32x4& q6, f32x4& q7) {
    asm volatile(
        "global_load_dwordx4 %0, %8, off\n\t"
        "global_load_dwordx4 %1, %9, off\n\t"
        "global_load_dwordx4 %2, %10, off\n\t"
        "global_load_dwordx4 %3, %11, off\n\t"
        "global_load_dwordx4 %4, %12, off\n\t"
        "global_load_dwordx4 %5, %13, off\n\t"
        "global_load_dwordx4 %6, %14, off\n\t"
        "global_load_dwordx4 %7, %15, off"
        : "=&v"(q0), "=&v"(q1), "=&v"(q2), "=&v"(q3),
          "=&v"(q4), "=&v"(q5), "=&v"(q6), "=&v"(q7)
        : "v"(p0), "v"(p1), "v"(p2), "v"(p3),
          "v"(p4), "v"(p5), "v"(p6), "v"(p7));
}

// counted waits with "+v" ties: consumers of r* are SSA-ordered after the
// wait, so the compiler cannot hoist them above it (rule-18-proof).
__device__ __forceinline__ void waitv8(
    f32x4& r0, f32x4& r1, f32x4& r2, f32x4& r3,
    f32x4& r4, f32x4& r5, f32x4& r6, f32x4& r7) {
    asm volatile("s_waitcnt vmcnt(8)"
        : "+v"(r0), "+v"(r1), "+v"(r2), "+v"(r3),
          "+v"(r4), "+v"(r5), "+v"(r6), "+v"(r7));
}
__device__ __forceinline__ void waitv0(
    f32x4& r0, f32x4& r1, f32x4& r2, f32x4& r3,
    f32x4& r4, f32x4& r5, f32x4& r6, f32x4& r7) {
    asm volatile("s_waitcnt vmcnt(0)"
        : "+v"(r0), "+v"(r1), "+v"(r2), "+v"(r3),
          "+v"(r4), "+v"(r5), "+v"(r6), "+v"(r7));
}

// --- K1: flag + weight->f32 concat + zero counts ---------------------------
__global__ void __launch_bounds__(256) k_prep(
    const void* __restrict__ r_ij,
    const void* w_rad, const void* b_rad, const void* w_direct,
    const void* w1, const void* b1, const void* w2, const void* b2,
    const void* w3, const void* b3, const void* w_v, const void* w_d,
    float* __restrict__ wcat, int* __restrict__ flag,
    int* __restrict__ counts, int N) {
    const int b = blockIdx.x;
    if (b == 0) {
        if (threadIdx.x == 0) flag[0] = detect_f32(r_ij) ? 1 : 0;
    } else if (b <= 11) {
        const bool f32 = detect_f32(r_ij);
        const void* src; int cnt; int off;
        switch (b) {
            case 1:  src = w_rad;    cnt = 256;  off = O_WRAD; break;
            case 2:  src = b_rad;    cnt = 32;   off = O_BRAD; break;
            case 3:  src = w_direct; cnt = 1024; off = O_WDIR; break;
            case 4:  src = w1;       cnt = 2048; off = O_W1;   break;
            case 5:  src = b1;       cnt = 64;   off = O_B1;   break;
            case 6:  src = w2;       cnt = 4096; off = O_W2;   break;
            case 7:  src = b2;       cnt = 64;   off = O_B2;   break;
            case 8:  src = w3;       cnt = 2048; off = O_W3;   break;
            case 9:  src = b3;       cnt = 32;   off = O_B3;   break;
            case 10: src = w_v;      cnt = 1024; off = O_WV;   break;
            default: src = w_d;      cnt = 1024; off = O_WD;   break;
        }
        for (int i = threadIdx.x; i < cnt; i += 256)
            wcat[off + i] = ldf(src, i, f32);
    } else {
        const int i = (b - 12) * 256 + threadIdx.x;
        if (i < N) counts[i] = 0;
    }
}

// --- K2: table build (from wcat) + per-edge rank atomics, one dispatch -----
__global__ void __launch_bounds__(64 * EPB) k_tabrank(
    const float* __restrict__ wcat, float* __restrict__ tabI,
    const int* __restrict__ src, int* __restrict__ counts,
    unsigned short* __restrict__ rank, int E) {
    __shared__ float Lh[EPB][32], Lt1[EPB][64], Lt2[EPB][64], Lrad[EPB][32];

    const int TB = TSIZE / EPB;
    if (blockIdx.x >= TB) {
        const int e = (blockIdx.x - TB) * 256 + threadIdx.x;
        if (e < E) rank[e] = (unsigned short)atomicAdd(&counts[src[e]], 1);
        return;
    }

    const int s = threadIdx.x >> 6;
    const int j = threadIdx.x & 63;
    const int e = blockIdx.x * EPB + s;
    const float d = (float)e * (DMAX / (float)(TSIZE - 1));

    float enc[8];
#pragma unroll
    for (int k = 0; k < 8; k++) {
        float t = (d - (float)k * (1.0f / 7.0f)) * 8.0f;
        enc[k] = expf(-t * t);
    }

    if (j < 32) {
        float hv = wcat[O_BRAD + j];
#pragma unroll
        for (int k = 0; k < 8; k++) hv = fmaf(enc[k], wcat[O_WRAD + k * 32 + j], hv);
        Lh[s][j] = hv;
    }
    __syncthreads();

    {
        float v = wcat[O_B1 + j];
#pragma unroll
        for (int i = 0; i < 32; i++) v = fmaf(Lh[s][i], wcat[O_W1 + i * 64 + j], v);
        Lt1[s][j] = lrelu(v);
    }
    __syncthreads();

    {
        float v = wcat[O_B2 + j];
#pragma unroll
        for (int i = 0; i < 64; i++) v = fmaf(Lt1[s][i], wcat[O_W2 + i * 64 + j], v);
        Lt2[s][j] = lrelu(v);
    }
    __syncthreads();

    if (j < 32) {
        float v = wcat[O_B3 + j];
#pragma unroll
        for (int i = 0; i < 64; i++) v = fmaf(Lt2[s][i], wcat[O_W3 + i * 32 + j], v);
#pragma unroll
        for (int i = 0; i < 32; i++) v = fmaf(Lh[s][i], wcat[O_WDIR + i * 32 + j], v);
        Lrad[s][j] = v;
    }
    __syncthreads();

    if (j < 32) {
        float sv = 0.0f, sd = 0.0f;
#pragma unroll
        for (int i = 0; i < 32; i++) {
            float ri = Lrad[s][i];
            sv = fmaf(ri, wcat[O_WV + i * 32 + j], sv);
            sd = fmaf(ri, wcat[O_WD + i * 32 + j], sd);
        }
        float* row = tabI + (size_t)e * ROWF + j * 4;
        row[0] = Lrad[s][j];
        row[1] = sv;
        row[2] = sd;
        row[3] = 0.0f;
    }
}

// --- K3: coarse sums over counts (64 nodes per block) ----------------------
__global__ void __launch_bounds__(64) k_sum(const int* __restrict__ counts,
                                            int* __restrict__ coarse, int N) {
    const int lane = threadIdx.x;
    const int n = blockIdx.x * 64 + lane;
    int s = (n < N) ? counts[n] : 0;
    for (int off = 32; off > 0; off >>= 1) s += __shfl_down(s, off);
    if (lane == 0) coarse[blockIdx.x] = s;
}

// --- K4: rowstart; coarse prefix summed cooperatively ----------------------
__global__ void __launch_bounds__(64) k_scan2c(const int* __restrict__ counts,
                                               const int* __restrict__ coarse,
                                               int* __restrict__ rowstart, int N) {
    const int lane = threadIdx.x;
    const int b = blockIdx.x;
    int cp = 0;
    for (int j = lane; j < b; j += 64) cp += coarse[j];
    for (int off = 32; off > 0; off >>= 1) cp += __shfl_down(cp, off);
    const int cpre = __shfl(cp, 0);

    const int n = b * 64 + lane;
    const int v = (n < N) ? counts[n] : 0;
    int inc = v;
    for (int off = 1; off < 64; off <<= 1) {
        int y = __shfl_up(inc, off);
        if (lane >= off) inc += y;
    }
    if (n < N) rowstart[n] = cpre + inc - v;
    if (n == N - 1) rowstart[N] = cpre + inc;
}

// --- K5: place payload (pos = rowstart[src] + rank) ------------------------
template <bool P16>
__global__ void __launch_bounds__(256) k_place2(
        const int* __restrict__ src, const unsigned short* __restrict__ rank,
        const int* __restrict__ rowstart, const void* __restrict__ r_ij,
        const int* __restrict__ flag, void* __restrict__ epsv, int E) {
    const bool f32 = flag[0] != 0;
    const int e = blockIdx.x * 256 + threadIdx.x;
    if (e >= E) return;
    const int pos = rowstart[src[e]] + (int)rank[e];
    const float x = ldf(r_ij, 3 * e + 0, f32);
    const float y = ldf(r_ij, 3 * e + 1, f32);
    const float z = ldf(r_ij, 3 * e + 2, f32);
    const float d2 = x * x + y * y + z * z;
    const float inv = rsqrtf(1.0f + 49.0f * d2);  // tens_sigmoid(7r)
    const float u = fminf(sqrtf(d2), DMAX) * ((float)(TSIZE - 1) / DMAX);
    const int ti = (int)(u + 0.5f);               // nearest, <= TSIZE-1
    const float rs0 = 7.0f * x * inv, rs1 = 7.0f * y * inv, rs2 = 7.0f * z * inv;
    if (P16) {
        ((float4*)epsv)[pos] =
            make_float4(rs0, rs1, rs2, __int_as_float(ti * ROWB));
    } else {
        const unsigned int h0 = __half_as_ushort(__float2half(rs0));
        const unsigned int h1 = __half_as_ushort(__float2half(rs1));
        const unsigned int h2 = __half_as_ushort(__float2half(rs2));
        ((uint2*)epsv)[pos] =
            make_uint2(h0 | (h1 << 16), h2 | ((unsigned)ti << 16));
    }
}

// --- K6: per-node accumulation: TWO nodes/wave, counted-vmcnt pipeline -----
#define ACC16(Q, U)                                                           \
    do {                                                                      \
        const float x = (Q).x, y = (Q).y, z = (Q).z;                          \
        accA += (U).x;                                                        \
        v0 += (U).y * x; v1 += (U).y * y; v2 += (U).y * z;                    \
        const float _tx = (U).z * x, _ty = (U).z * y, _tz = (U).z * z;        \
        d00 += _tx * x; d01 += _tx * y; d02 += _tx * z;                       \
        d10 += _ty * x; d11 += _ty * y; d12 += _ty * z;                       \
        d20 += _tz * x; d21 += _tz * y; d22 += _tz * z;                       \
    } while (0)

#define P8ARGS(R) R##0, R##1, R##2, R##3, R##4, R##5, R##6, R##7
#define LOADP_NW(R, IDX)                                                      \
    do { const char* _pp = (const char*)epsv + (size_t)(IDX) * 16;            \
         load8x16_nw(_pp, _pp + 16, _pp + 32, _pp + 48,                       \
                     _pp + 64, _pp + 80, _pp + 96, _pp + 112, P8ARGS(R));     \
    } while (0)
#define LOADT_NW(R, Q)                                                        \
    load8x16_nw(tabA + __float_as_int((Q##0).w),                              \
                tabA + __float_as_int((Q##1).w),                              \
                tabA + __float_as_int((Q##2).w),                              \
                tabA + __float_as_int((Q##3).w),                              \
                tabA + __float_as_int((Q##4).w),                              \
                tabA + __float_as_int((Q##5).w),                              \
                tabA + __float_as_int((Q##6).w),                              \
                tabA + __float_as_int((Q##7).w),                              \
                P8ARGS(R))
#define ACCB(Q, T)                                                            \
    do { ACC16(Q##0, T##0); ACC16(Q##1, T##1); ACC16(Q##2, T##2);             \
         ACC16(Q##3, T##3); ACC16(Q##4, T##4); ACC16(Q##5, T##5);             \
         ACC16(Q##6, T##6); ACC16(Q##7, T##7); } while (0)

template <bool P16>
__global__ void __launch_bounds__(64 * NPB, 3) k_nodes2(
    const void* __restrict__ epsv,
    const int* __restrict__ rowstart,
    const float* __restrict__ tabI,
    const int* __restrict__ flag,
    void* __restrict__ out, int N) {
    const int wave = threadIdx.x >> 6;
    const int lane = threadIdx.x & 63;
    const int n0 = (blockIdx.x * NPB + wave) * 2;
    const int a = lane & 31;
    const int half = lane >> 5;
    const int myn = n0 + half;
    const bool f32 = flag[0] != 0;
    const char* tabA = (const char*)tabI + a * 16;   // 16-B quad base

    int s0 = 0, s1 = 0;
    if (myn < N) { s0 = rowstart[myn]; s1 = rowstart[myn + 1]; }
    const int mylen = s1 - s0;
    const int lenA = __shfl(mylen, 0);
    const int lenB = __shfl(mylen, 32);
    const int minl = min(lenA, lenB);
    const int maxl = max(lenA, lenB);
    const int mclamp = max(mylen - 1, 0);

    float accA = 0.f, v0 = 0.f, v1 = 0.f, v2 = 0.f;
    float d00 = 0.f, d01 = 0.f, d02 = 0.f,
          d10 = 0.f, d11 = 0.f, d12 = 0.f,
          d20 = 0.f, d21 = 0.f, d22 = 0.f;

    if (P16) {
        int i = 0;
        if (minl >= 8) {
            f32x4 pa0, pa1, pa2, pa3, pa4, pa5, pa6, pa7;
            f32x4 pb0, pb1, pb2, pb3, pb4, pb5, pb6, pb7;
            f32x4 tt0, tt1, tt2, tt3, tt4, tt5, tt6, tt7;
            LOADP_NW(pa, s0);
            waitv0(P8ARGS(pa));
            for (; i + 24 <= minl; i += 16) {
                LOADT_NW(tt, pa);
                LOADP_NW(pb, s0 + i + 8);
                waitv8(P8ARGS(tt));
                ACCB(pa, tt);
                waitv0(P8ARGS(pb));
                LOADT_NW(tt, pb);
                LOADP_NW(pa, s0 + i + 16);
                waitv8(P8ARGS(tt));
                ACCB(pb, tt);
                waitv0(P8ARGS(pa));
            }
            if (i + 16 <= minl) {          // two batches left
                LOADT_NW(tt, pa);
                LOADP_NW(pb, s0 + i + 8);
                waitv8(P8ARGS(tt));
                ACCB(pa, tt);
                waitv0(P8ARGS(pb));
                LOADT_NW(tt, pb);
                waitv0(P8ARGS(tt));
                ACCB(pb, tt);
                i += 16;
            } else {                        // one batch left
                LOADT_NW(tt, pa);
                waitv0(P8ARGS(tt));
                ACCB(pa, tt);
                i += 8;
            }
        }
        // ---- remainder: predicated 8-wide batches up to maxl ----
        for (; i < maxl; i += 8) {
            float m0, m1, m2, m3, m4, m5, m6, m7;
#define TIDX(K) ((i + K) < mylen ? (i + K) : mclamp)
#define TPTR(K) ((const char*)epsv + (size_t)(s0 + TIDX(K)) * 16)
            m0 = (i + 0 < mylen) ? 1.f : 0.f;
            m1 = (i + 1 < mylen) ? 1.f : 0.f;
            m2 = (i + 2 < mylen) ? 1.f : 0.f;
            m3 = (i + 3 < mylen) ? 1.f : 0.f;
            m4 = (i + 4 < mylen) ? 1.f : 0.f;
            m5 = (i + 5 < mylen) ? 1.f : 0.f;
            m6 = (i + 6 < mylen) ? 1.f : 0.f;
            m7 = (i + 7 < mylen) ? 1.f : 0.f;
            f32x4 q0, q1, q2, q3, q4, q5, q6, q7;
            load8x16(TPTR(0), TPTR(1), TPTR(2), TPTR(3),
                     TPTR(4), TPTR(5), TPTR(6), TPTR(7),
                     q0, q1, q2, q3, q4, q5, q6, q7);
#undef TPTR
#undef TIDX
            f32x4 u0, u1, u2, u3, u4, u5, u6, u7;
            load8x16(tabA + __float_as_int(q0.w), tabA + __float_as_int(q1.w),
                     tabA + __float_as_int(q2.w), tabA + __float_as_int(q3.w),
                     tabA + __float_as_int(q4.w), tabA + __float_as_int(q5.w),
                     tabA + __float_as_int(q6.w), tabA + __float_as_int(q7.w),
                     u0, u1, u2, u3, u4, u5, u6, u7);
#define SAPX(K)                                                               \
            do { f32x4 uu = u##K; uu.x *= m##K; uu.y *= m##K; uu.z *= m##K;   \
                 ACC16(q##K, uu); } while (0)
            SAPX(0); SAPX(1); SAPX(2); SAPX(3);
            SAPX(4); SAPX(5); SAPX(6); SAPX(7);
#undef SAPX
        }
    } else {
        // ---- P8 fallback payload path (plain C, rarely used) ----
        for (int i = 0; i < maxl; i++) {
            if (i < mylen) {
                const u32x2 qh = *((const u32x2*)epsv + (s0 + i));
                const float x = __half2float(__ushort_as_half(
                    (unsigned short)(qh.x & 0xffffu)));
                const float y = __half2float(__ushort_as_half(
                    (unsigned short)(qh.x >> 16)));
                const float z = __half2float(__ushort_as_half(
                    (unsigned short)(qh.y & 0xffffu)));
                const TE t = *(const TE*)(tabA + (int)(qh.y >> 16) * ROWB);
                accA += t.r;
                v0 += t.v * x; v1 += t.v * y; v2 += t.v * z;
                const float _tx = t.d * x, _ty = t.d * y, _tz = t.d * z;
                d00 += _tx * x; d01 += _tx * y; d02 += _tx * z;
                d10 += _ty * x; d11 += _ty * y; d12 += _ty * z;
                d20 += _tz * x; d21 += _tz * y; d22 += _tz * z;
            }
        }
    }

    if (myn >= N) return;
    const size_t baseV = (size_t)N * 32;
    const size_t baseD = (size_t)N * 128;
    stf(out, (size_t)myn * 32 + a, accA, f32);
    const size_t vb = baseV + (size_t)myn * 96 + a * 3;
    stf(out, vb + 0, v0, f32);
    stf(out, vb + 1, v1, f32);
    stf(out, vb + 2, v2, f32);
    const size_t db = baseD + (size_t)myn * 288 + a * 9;
    stf(out, db + 0, d00, f32);
    stf(out, db + 1, d01, f32);
    stf(out, db + 2, d02, f32);
    stf(out, db + 3, d10, f32);
    stf(out, db + 4, d11, f32);
    stf(out, db + 5, d12, f32);
    stf(out, db + 6, d20, f32);
    stf(out, db + 7, d21, f32);
    stf(out, db + 8, d22, f32);
}

// --- fallback (ws too small for payload): perm + on-the-fly recompute ------
__global__ void __launch_bounds__(256) k_place_g(
        const int* __restrict__ src, const unsigned short* __restrict__ rank,
        const int* __restrict__ rowstart, int* __restrict__ perm, int E) {
    const int e = blockIdx.x * 256 + threadIdx.x;
    if (e < E) perm[rowstart[src[e]] + (int)rank[e]] = e;
}
__global__ void __launch_bounds__(256) k_nodes_fb(
    const int* __restrict__ perm, const void* __restrict__ r_ij,
    const int* __restrict__ rowstart, const float* __restrict__ tabI,
    const int* __restrict__ flag, void* __restrict__ out, int N) {
    const int wave = threadIdx.x >> 6;
    const int lane = threadIdx.x & 63;
    const int n = blockIdx.x * 4 + wave;
    if (n >= N) return;
    const int a = lane & 31;
    const bool hi = (lane >> 5) != 0;
    const bool f32 = flag[0] != 0;
    const int s0 = rowstart[n], s1 = rowstart[n + 1];
    float accR = 0.f, acc1 = 0.f, acc2 = 0.f, acc3 = 0.f,
          acc4 = 0.f, acc5 = 0.f, acc6 = 0.f;
    for (int idx = s0; idx < s1; idx++) {
        const int e = perm[idx];
        const float x0 = ldf(r_ij, 3 * e + 0, f32);
        const float y0 = ldf(r_ij, 3 * e + 1, f32);
        const float z0 = ldf(r_ij, 3 * e + 2, f32);
        const float d2 = x0 * x0 + y0 * y0 + z0 * z0;
        const float inv = rsqrtf(1.0f + 49.0f * d2);
        const float x = 7.0f * x0 * inv, y = 7.0f * y0 * inv, z = 7.0f * z0 * inv;
        const float u = fminf(sqrtf(d2), DMAX) * ((float)(TSIZE - 1) / DMAX);
        const int b = (int)(u + 0.5f) * ROWF + a * 4;   // padded row
        const float ra = tabI[b], rv = tabI[b + 1], rd = tabI[b + 2];
        const float b1 = (hi ? rd : rv) * (hi ? y : 1.0f);
        const float b2 = rd * (hi ? z : x);
        accR += ra;
        acc1 += b1 * x; acc2 += b1 * y; acc3 += b1 * z;
        acc4 += b2 * x; acc5 += b2 * y; acc6 += b2 * z;
    }
    const size_t baseV = (size_t)N * 32;
    const size_t baseD = (size_t)N * 128;
    if (!hi) {
        stf(out, (size_t)n * 32 + a, accR, f32);
        const size_t vb = baseV + (size_t)n * 96 + a * 3;
        stf(out, vb + 0, acc1, f32);
        stf(out, vb + 1, acc2, f32);
        stf(out, vb + 2, acc3, f32);
        const size_t db = baseD + (size_t)n * 288 + a * 9;
        stf(out, db + 0, acc4, f32);
        stf(out, db + 1, acc5, f32);
        stf(out, db + 2, acc6, f32);
    } else {
        const size_t db = baseD + (size_t)n * 288 + a * 9;
        stf(out, db + 3, acc1, f32);
        stf(out, db + 4, acc2, f32);
        stf(out, db + 5, acc3, f32);
        stf(out, db + 6, acc4, f32);
        stf(out, db + 7, acc5, f32);
        stf(out, db + 8, acc6, f32);
    }
}

extern "C" void kernel_launch(void* const* d_in, const int* in_sizes, int n_in,
                              void* d_out, int out_size, void* d_ws, size_t ws_size,
                              hipStream_t stream) {
    const void* r_ij     = d_in[0];
    const void* w_rad    = d_in[1];
    const void* b_rad    = d_in[2];
    const void* w_direct = d_in[3];
    const void* w1       = d_in[4];
    const void* b1       = d_in[5];
    const void* w2       = d_in[6];
    const void* b2       = d_in[7];
    const void* w3       = d_in[8];
    const void* b3       = d_in[9];
    const void* w_v      = d_in[10];
    const void* w_d      = d_in[11];
    const int* edges_src = (const int*)d_in[12];

    const int E = in_sizes[12];
    const int N = out_size / 416;   // 32 + 96 + 288 per node
    const int TB = TSIZE / EPB;
    const int ZB = (N + 255) / 256;                    // counts-zero blocks
    const int EB = (E + 255) / 256;                    // per-edge blocks
    const int NB = (N + 63) / 64;                      // 64-node blocks
    const int nodeBlocks = (N + 2 * NPB - 1) / (2 * NPB);

    // tail: wcat + flag(pad 4) + tabI 4MB + counts N + rowstart N+1
    //       + coarse NB + rank E u16
    const size_t tailBytes = ((size_t)W_TOT + 4) * 4 + (size_t)TSIZE * ROWF * 4
                           + ((size_t)N + N + 1 + NB) * 4 + (size_t)E * 2 + 64;
    const bool p16 = ws_size >= (size_t)E * 16 + tailBytes;
    const bool p8  = !p16 && ws_size >= (size_t)E * 8 + tailBytes;

    char* w = (char*)d_ws;
    if (p16 || p8) {
        const size_t slot = (size_t)E * (p16 ? 16 : 8);
        void* eps      = (void*)w;
        float* wcat    = (float*)(w + slot);
        int* flag      = (int*)(wcat + W_TOT);
        float* tabI    = (float*)(flag + 4);            // 16-B aligned
        int* counts    = (int*)(tabI + (size_t)TSIZE * ROWF);
        int* rowstart  = counts + N;          // N+1
        int* coarse    = rowstart + N + 1;    // NB
        unsigned short* rank = (unsigned short*)(coarse + NB);   // E u16

        k_prep<<<12 + ZB, 256, 0, stream>>>(
            r_ij, w_rad, b_rad, w_direct, w1, b1, w2, b2, w3, b3, w_v, w_d,
            wcat, flag, counts, N);
        k_tabrank<<<TB + EB, 64 * EPB, 0, stream>>>(
            wcat, tabI, edges_src, counts, rank, E);
        k_sum<<<NB, 64, 0, stream>>>(counts, coarse, N);
        k_scan2c<<<NB, 64, 0, stream>>>(counts, coarse, rowstart, N);
        if (p16) {
            k_place2<true><<<EB, 256, 0, stream>>>(
                edges_src, rank, rowstart, r_ij, flag, eps, E);
            k_nodes2<true><<<nodeBlocks, 64 * NPB, 0, stream>>>(
                eps, rowstart, tabI, flag, d_out, N);
        } else {
            k_place2<false><<<EB, 256, 0, stream>>>(
                edges_src, rank, rowstart, r_ij, flag, eps, E);
            k_nodes2<false><<<nodeBlocks, 64 * NPB, 0, stream>>>(
                eps, rowstart, tabI, flag, d_out, N);
        }
    } else {
        // fallback: perm-indexed nodes, on-the-fly recompute
        int* perm      = (int*)w;             // E
        float* wcat    = (float*)(w + (size_t)E * 4);
        int* flag      = (int*)(wcat + W_TOT);
        float* tabI    = (float*)(flag + 4);
        int* counts    = (int*)(tabI + (size_t)TSIZE * ROWF);
        int* rowstart  = counts + N;          // N+1
        int* coarse    = rowstart + N + 1;    // NB
        unsigned short* rank = (unsigned short*)(coarse + NB);   // E u16

        k_prep<<<12 + ZB, 256, 0, stream>>>(
            r_ij, w_rad, b_rad, w_direct, w1, b1, w2, b2, w3, b3, w_v, w_d,
            wcat, flag, counts, N);
        k_tabrank<<<TB + EB, 64 * EPB, 0, stream>>>(
            wcat, tabI, edges_src, counts, rank, E);
        k_sum<<<NB, 64, 0, stream>>>(counts, coarse, N);
        k_scan2c<<<NB, 64, 0, stream>>>(counts, coarse, rowstart, N);
        k_place_g<<<EB, 256, 0, stream>>>(edges_src, rank, rowstart, perm, E);
        k_nodes_fb<<<(N + 3) / 4, 256, 0, stream>>>(
            perm, r_ij, rowstart, tabI, flag, d_out, N);
    }
}